// Round 6
// baseline (2125.862 us; speedup 1.0000x reference)
//
#include <hip/hip_runtime.h>
#include <math.h>

constexpr int TS = 16;     // samples per block
constexpr int NT = 512;    // threads per block (8 waves)
constexpr int SSTRIDE = 776;   // bf16 per sample, HID0 state (768 + 8 pad)
constexpr int H1S = 1544;      // bf16 per sample, HID1 transient (1536 + 8 pad)
constexpr int BUF = TS*SSTRIDE;
// HID0 per-sample layout: l0 @0 (64: [u]), l1 @64 (3x64: [i][u]),
// l2 @256 (5x64), l1b @576 (3x64)
// HID1 layout: l0 @0 (128), l1 @128 (3x128), l2 @512 (5x128), l1b @1152 (3x128)

typedef __attribute__((ext_vector_type(8))) short bf16x8;
typedef __attribute__((ext_vector_type(4))) float f32x4;

__device__ inline f32x4 mfma16(bf16x8 a, bf16x8 b, f32x4 c){
  return __builtin_amdgcn_mfma_f32_16x16x32_bf16(a, b, c, 0, 0, 0);
}
__device__ inline unsigned short f2b(float f){
  union { float f; unsigned u; } v; v.f = f;
  return (unsigned short)((v.u + 0x7fffu + ((v.u >> 16) & 1u)) >> 16);
}
__device__ inline float b2f(unsigned short h){
  union { unsigned u; float f; } v; v.u = ((unsigned)h) << 16; return v.f;
}
__device__ inline void store_hl(unsigned short* ph, unsigned short* pl, int idx, float v){
  unsigned short h = f2b(v);
  ph[idx] = h;
  pl[idx] = f2b(v - b2f(h));
}
#define LDFRAG(p) (*(const bf16x8*)(p))

// ws bf16 weight offsets (elements, base = ws+4096B). lo plane at +W_TOT.
constexpr int OFF_L2W0 = 0;        // 64x128 (WT[o][k])
constexpr int OFF_L2W1 = 8192;     // 128x256
constexpr int OFF_L2W2 = 40960;    // 64x128
constexpr int OFF_LW0  = 49152;    // 11 x 64x64
constexpr int OFF_LW1  = 94208;    // 11 x 128x128
constexpr int OFF_LW2  = 274432;   // 11 x 64x64
constexpr int OFF_TPW  = 319488;   // 3x14 x 64x64 ([u][v])
constexpr int OFF_TP4W = 491520;   // 17 x 64x64
constexpr int W_TOT    = 561152;

// ============================================================================
// Clebsch-Gordan init (element-parallel fp64; verified R2-R5)
// offsets: 0:(0,0,0)@0 1:(0,1,1)@1 2:(1,0,1)@10 3:(0,2,2)@19 4:(2,0,2)@44
// 5:(1,1,0)@69 6:(1,1,1)@78 7:(1,1,2)@105 8:(2,1,2)@150 9:(1,2,2)@225
// 10:(2,2,0)@300 11:(2,2,1)@325 12:(2,2,2)@400 ; total 525 floats
// ============================================================================
__device__ inline double dfact(int n){ double r=1.0; for(int i=2;i<=n;i++) r*=(double)i; return r; }
struct dcplx { double x, y; };
__device__ inline dcplx cmul(dcplx a, dcplx b){ return {a.x*b.x-a.y*b.y, a.x*b.y+a.y*b.x}; }

__device__ dcplx Uent(int l, int r, int c){
  double re=0.0, im=0.0;
  double s = 1.0/sqrt(2.0);
  if (r==l && c==l) re = 1.0;
  else if (c>l){ int m=c-l; double sgn=(m&1)?-1.0:1.0;
    if (r==l-m) re = s; else if (r==l+m) re = sgn*s;
  } else if (c<l){ int m=l-c; double sgn=(m&1)?-1.0:1.0;
    if (r==l-m) im = s; else if (r==l+m) im = -sgn*s;
  }
  int lm=l&3; double pr,pi;
  if(lm==0){pr=1;pi=0;} else if(lm==1){pr=0;pi=-1;} else if(lm==2){pr=-1;pi=0;} else {pr=0;pi=1;}
  return { re*pr-im*pi, re*pi+im*pr };
}

__device__ double cg_complex_entry(int l1,int l2,int l3,int m1,int m2){
  int m3=m1+m2;
  if (m3<-l3 || m3>l3) return 0.0;
  double pref = sqrt((double)(2*l3+1)*dfact(l3+l1-l2)*dfact(l3-l1+l2)*dfact(l1+l2-l3)/dfact(l1+l2+l3+1));
  pref *= sqrt(dfact(l3+m3)*dfact(l3-m3)*dfact(l1-m1)*dfact(l1+m1)*dfact(l2-m2)*dfact(l2+m2));
  double s=0.0;
  for(int k=0;k<=l1+l2-l3;k++){
    int a2=l1-m1-k, a3=l2+m2-k, a4=l3-l2+m1+k, a5=l3-l1-m2+k;
    if(a2<0||a3<0||a4<0||a5<0) continue;
    double t=1.0/(dfact(k)*dfact(l1+l2-l3-k)*dfact(a2)*dfact(a3)*dfact(a4)*dfact(a5));
    s += (k&1)? -t : t;
  }
  return pref*s;
}

__global__ void cg_init_kernel(float* cg){
  __shared__ double sKr[525], sKi[525];
  __shared__ double sScale[13];
  __shared__ int    sSel[13];
  const int L1[13]={0,0,1,0,2,1,1,1,2,1,2,2,2};
  const int L2[13]={0,1,0,2,0,1,1,1,1,2,2,2,2};
  const int L3[13]={0,1,1,2,2,0,1,2,2,2,0,1,2};
  const int OFF[14]={0,1,10,19,44,69,78,105,150,225,300,325,400,525};
  const int tid = threadIdx.x;
  int combo=-1, l1=0,l2=0,l3=0;
  if (tid < 525){
    combo=12;
    for(int i=0;i<12;i++) if (tid < OFF[i+1]) { combo=i; break; }
    l1=L1[combo]; l2=L2[combo]; l3=L3[combo];
    int d2=2*l2+1, d3=2*l3+1;
    int e = tid - OFF[combo];
    int a = e/(d2*d3), b=(e/d3)%d2, cc=e%d3;
    double kr=0.0, ki=0.0;
    for(int m=0;m<2*l1+1;m++) for(int n=0;n<d2;n++){
      int m3 = (m-l1)+(n-l2);
      if (m3<-l3||m3>l3) continue;
      double cv = cg_complex_entry(l1,l2,l3,m-l1,n-l2);
      if (cv==0.0) continue;
      dcplx u1=Uent(l1,m,a), u2=Uent(l2,n,b), u3=Uent(l3,m3+l3,cc);
      u3.y = -u3.y;
      dcplx t = cmul(cmul(u1,u2),u3);
      kr += t.x*cv; ki += t.y*cv;
    }
    sKr[tid]=kr; sKi[tid]=ki;
  }
  __syncthreads();
  if (tid < 13){
    int sz = OFF[tid+1]-OFF[tid];
    double nr=0,ni=0;
    for(int i=0;i<sz;i++){ double r=sKr[OFF[tid]+i], im=sKi[OFF[tid]+i]; nr+=r*r; ni+=im*im; }
    int sel = (nr>=ni)? 0 : 1;
    sSel[tid]=sel;
    sScale[tid] = sqrt((double)(2*L3[tid]+1))/sqrt(sel? ni : nr);
  }
  __syncthreads();
  if (tid < 525){
    double v = sSel[combo]? sKi[tid] : sKr[tid];
    cg[tid] = (float)(v*sScale[combo]);
  }
}

// ============================================================================
// Weight prep: fp32 -> bf16 hi/lo planes. Linear weights transposed WT[o][k];
// TP weights [u][v].
// ============================================================================
__global__ void prep_kernel(const float* __restrict__ l2W0, const float* __restrict__ l2W1,
                            const float* __restrict__ l2W2, const float* __restrict__ LW0,
                            const float* __restrict__ LW1, const float* __restrict__ LW2,
                            const float* __restrict__ tpw, const float* __restrict__ tp4w,
                            unsigned short* __restrict__ wb){
  int i = blockIdx.x*256 + threadIdx.x;
  if (i >= W_TOT) return;
  float v;
  if (i < 8192){ int o=i>>7, k=i&127; v = l2W0[k*64+o]; }
  else if (i < 40960){ int j=i-8192; int o=j>>8, k=j&255; v = l2W1[k*128+o]; }
  else if (i < 49152){ int j=i-40960; int o=j>>7, k=j&127; v = l2W2[k*64+o]; }
  else if (i < 94208){ int j=i-49152; int li=j>>12, r=j&4095, o=r>>6, k=r&63; v = LW0[li*4096+k*64+o]; }
  else if (i < 274432){ int j=i-94208; int li=j>>14, r=j&16383, o=r>>7, k=r&127; v = LW1[li*16384+k*128+o]; }
  else if (i < 319488){ int j=i-274432; int li=j>>12, r=j&4095, o=r>>6, k=r&63; v = LW2[li*4096+k*64+o]; }
  else if (i < 491520){ v = tpw[i-319488]; }
  else { v = tp4w[i-491520]; }
  unsigned short h = f2b(v);
  wb[i] = h;
  wb[W_TOT + i] = f2b(v - b2f(h));
}

// ============================================================================
// MFMA linear HID0->HID0 (hi/lo). Jobs: 0..3 l0 | 4..11 l1 | 12..15 l2.
// ============================================================================
__device__ void linL_mfma(const unsigned short* __restrict__ wb, int o0, int o1, int o2,
                          const float* __restrict__ b0,
                          const unsigned short* sh, const unsigned short* sl,
                          unsigned short* dh, unsigned short* dl, int wave, int lane)
{
  const float rs128 = 0.08838834764831845f;
  int l16 = lane & 15, quad = lane >> 4;
  int abase = l16 * SSTRIDE;
  for (int job = wave; job < 16; job += 8){
    if (job < 4){                 // l0: K=64, /8 + bias
      int col = job*16 + l16;
      f32x4 a0 = {0,0,0,0}, a1 = {0,0,0,0};
      #pragma unroll
      for (int ks=0; ks<2; ks++){
        int so = abase + ks*32 + quad*8;
        bf16x8 xh = LDFRAG(sh+so), xl = LDFRAG(sl+so);
        int wo = o0 + col*64 + ks*32 + quad*8;
        bf16x8 wh = LDFRAG(wb+wo), wl = LDFRAG(wb+W_TOT+wo);
        a0 = mfma16(xh,wh,a0); a1 = mfma16(xh,wl,a1); a1 = mfma16(xl,wh,a1);
      }
      float bias = b0[col];
      #pragma unroll
      for (int r=0;r<4;r++)
        store_hl(dh,dl,(quad*4+r)*SSTRIDE + col, (a0[r]+a1[r])*0.125f + bias);
    } else if (job < 12){         // l1: K=128 (l1|l1b), /sqrt(128)
      int nt = job-4; int col = nt*16 + l16;
      #pragma unroll
      for (int i=0;i<3;i++){
        f32x4 a0 = {0,0,0,0}, a1 = {0,0,0,0};
        #pragma unroll
        for (int ks=0; ks<4; ks++){
          int ka = ks*32 + quad*8;
          int so = abase + ((ka < 64) ? (64 + i*64 + ka) : (576 + i*64 + ka - 64));
          bf16x8 xh = LDFRAG(sh+so), xl = LDFRAG(sl+so);
          int wo = o1 + col*128 + ka;
          bf16x8 wh = LDFRAG(wb+wo), wl = LDFRAG(wb+W_TOT+wo);
          a0 = mfma16(xh,wh,a0); a1 = mfma16(xh,wl,a1); a1 = mfma16(xl,wh,a1);
        }
        int dof = (col < 64) ? (64 + i*64 + col) : (576 + i*64 + col - 64);
        #pragma unroll
        for (int r=0;r<4;r++)
          store_hl(dh,dl,(quad*4+r)*SSTRIDE + dof, (a0[r]+a1[r])*rs128);
      }
    } else {                      // l2: K=64, /8
      int nt = job-12; int col = nt*16 + l16;
      #pragma unroll
      for (int i=0;i<5;i++){
        f32x4 a0 = {0,0,0,0}, a1 = {0,0,0,0};
        #pragma unroll
        for (int ks=0; ks<2; ks++){
          int so = abase + 256 + i*64 + ks*32 + quad*8;
          bf16x8 xh = LDFRAG(sh+so), xl = LDFRAG(sl+so);
          int wo = o2 + col*64 + ks*32 + quad*8;
          bf16x8 wh = LDFRAG(wb+wo), wl = LDFRAG(wb+W_TOT+wo);
          a0 = mfma16(xh,wh,a0); a1 = mfma16(xh,wl,a1); a1 = mfma16(xl,wh,a1);
        }
        #pragma unroll
        for (int r=0;r<4;r++)
          store_hl(dh,dl,(quad*4+r)*SSTRIDE + 256 + i*64 + col, (a0[r]+a1[r])*0.125f);
      }
    }
  }
}

// lin2: HID1 -> HID0 (K=128/256/128), hi/lo
__device__ void lin2_mfma(const unsigned short* __restrict__ wb,
                          const float* __restrict__ b0,
                          const unsigned short* h1h, const unsigned short* h1l,
                          unsigned short* dh, unsigned short* dl, int wave, int lane)
{
  const float rs128 = 0.08838834764831845f;
  int l16 = lane & 15, quad = lane >> 4;
  int abase = l16 * H1S;
  for (int job = wave; job < 16; job += 8){
    if (job < 4){                 // l0: K=128
      int col = job*16 + l16;
      f32x4 a0 = {0,0,0,0}, a1 = {0,0,0,0};
      #pragma unroll
      for (int ks=0; ks<4; ks++){
        int so = abase + ks*32 + quad*8;
        bf16x8 xh = LDFRAG(h1h+so), xl = LDFRAG(h1l+so);
        int wo = OFF_L2W0 + col*128 + ks*32 + quad*8;
        bf16x8 wh = LDFRAG(wb+wo), wl = LDFRAG(wb+W_TOT+wo);
        a0 = mfma16(xh,wh,a0); a1 = mfma16(xh,wl,a1); a1 = mfma16(xl,wh,a1);
      }
      float bias = b0[col];
      #pragma unroll
      for (int r=0;r<4;r++)
        store_hl(dh,dl,(quad*4+r)*SSTRIDE + col, (a0[r]+a1[r])*rs128 + bias);
    } else if (job < 12){         // l1: K=256, /16
      int nt = job-4; int col = nt*16 + l16;
      #pragma unroll
      for (int i=0;i<3;i++){
        f32x4 a0 = {0,0,0,0}, a1 = {0,0,0,0};
        #pragma unroll
        for (int ks=0; ks<8; ks++){
          int ka = ks*32 + quad*8;
          int so = abase + ((ka < 128) ? (128 + i*128 + ka) : (1152 + i*128 + ka - 128));
          bf16x8 xh = LDFRAG(h1h+so), xl = LDFRAG(h1l+so);
          int wo = OFF_L2W1 + col*256 + ka;
          bf16x8 wh = LDFRAG(wb+wo), wl = LDFRAG(wb+W_TOT+wo);
          a0 = mfma16(xh,wh,a0); a1 = mfma16(xh,wl,a1); a1 = mfma16(xl,wh,a1);
        }
        int dof = (col < 64) ? (64 + i*64 + col) : (576 + i*64 + col - 64);
        #pragma unroll
        for (int r=0;r<4;r++)
          store_hl(dh,dl,(quad*4+r)*SSTRIDE + dof, (a0[r]+a1[r])*0.0625f);
      }
    } else {                      // l2: K=128
      int nt = job-12; int col = nt*16 + l16;
      #pragma unroll
      for (int i=0;i<5;i++){
        f32x4 a0 = {0,0,0,0}, a1 = {0,0,0,0};
        #pragma unroll
        for (int ks=0; ks<4; ks++){
          int so = abase + 512 + i*128 + ks*32 + quad*8;
          bf16x8 xh = LDFRAG(h1h+so), xl = LDFRAG(h1l+so);
          int wo = OFF_L2W2 + col*128 + ks*32 + quad*8;
          bf16x8 wh = LDFRAG(wb+wo), wl = LDFRAG(wb+W_TOT+wo);
          a0 = mfma16(xh,wh,a0); a1 = mfma16(xh,wl,a1); a1 = mfma16(xl,wh,a1);
        }
        #pragma unroll
        for (int r=0;r<4;r++)
          store_hl(dh,dl,(quad*4+r)*SSTRIDE + 256 + i*64 + col, (a0[r]+a1[r])*rs128);
      }
    }
  }
}

// ============================================================================
// Wave-local TP chunk (NO barriers): wave owns samples 2w, 2w+1.
// b = W(64x64) x x2-cols packed into the N dim (col = 2*jj+p, p=sample parity);
// D transposed through private per-wave LDS scratch (in-order same-wave ds ops),
// then scalar CG partial contraction. CG coeffs from global (uniform s_load).
// ============================================================================
template<int D1,int D2,int D3,int JC,int J0,int O1,int O2,int CGO>
__device__ __forceinline__ void tp_chunk(
    const unsigned short* __restrict__ wb, int wo,
    const unsigned short* s1h, const unsigned short* s1l,
    const unsigned short* s2h, const unsigned short* s2l,
    float* wscr, const float* __restrict__ cgp,
    float* tk0, float* tk1, int wave, int lane)
{
  int l16 = lane & 15, quad = lane >> 4;
  // ---- b-staging: full-wave MFMAs, cols = (jj, p) for this wave's 2 samples
  {
    int jj = l16 >> 1, p = l16 & 1;
    bool colok = (l16 < 2*JC);
    int j = J0 + (colok ? jj : 0);
    int n = 2*wave + p;
    int sofs = n*SSTRIDE + O2 + j*64 + quad*8;
    bf16x8 B0h = LDFRAG(s2h + sofs),      B0l = LDFRAG(s2l + sofs);
    bf16x8 B1h = LDFRAG(s2h + sofs + 32), B1l = LDFRAG(s2l + sofs + 32);
    #pragma unroll
    for (int mt=0; mt<4; mt++){
      int wofs = wo + (mt*16 + l16)*64 + quad*8;
      bf16x8 W0h = LDFRAG(wb + wofs),          W0l = LDFRAG(wb + W_TOT + wofs);
      bf16x8 W1h = LDFRAG(wb + wofs + 32),     W1l = LDFRAG(wb + W_TOT + wofs + 32);
      f32x4 a0 = {0,0,0,0}, a1 = {0,0,0,0};
      a0 = mfma16(W0h,B0h,a0); a1 = mfma16(W0h,B0l,a1); a1 = mfma16(W0l,B0h,a1);
      a0 = mfma16(W1h,B1h,a0); a1 = mfma16(W1h,B1l,a1); a1 = mfma16(W1l,B1h,a1);
      if (colok){
        f32x4 s;
        #pragma unroll
        for (int r=0;r<4;r++) s[r] = a0[r]+a1[r];
        *(f32x4*)&wscr[l16*68 + mt*16 + quad*4] = s;  // [col][u], 68-pad
      }
    }
  }
  // ---- CG partial contraction (reads own wave's scratch; same-wave order)
  #pragma unroll
  for (int p=0; p<2; p++){
    int n = 2*wave + p;
    float* tk = p ? tk1 : tk0;
    float x1v[D1], bv[JC];
    #pragma unroll
    for (int i=0;i<D1;i++){
      int o = n*SSTRIDE + O1 + i*64 + lane;
      x1v[i] = b2f(s1h[o]) + b2f(s1l[o]);
    }
    #pragma unroll
    for (int jj=0;jj<JC;jj++) bv[jj] = wscr[(2*jj+p)*68 + lane];
    #pragma unroll
    for (int i=0;i<D1;i++){
      #pragma unroll
      for (int jj=0;jj<JC;jj++){
        float pr = x1v[i]*bv[jj];
        #pragma unroll
        for (int k=0;k<D3;k++) tk[k] += pr*cgp[CGO + (i*D2 + J0+jj)*D3 + k];
      }
    }
  }
}

template<int D1,int D2,int D3,int O1,int O2,int CGO>
__device__ __forceinline__ void tp_path(
    const unsigned short* __restrict__ wb, int wo,
    const unsigned short* s1h, const unsigned short* s1l,
    const unsigned short* s2h, const unsigned short* s2l,
    float* wscr, const float* __restrict__ cgp,
    float* tk0, float* tk1, int wave, int lane)
{
  if constexpr (D2 <= 3){
    tp_chunk<D1,D2,D3,D2,0,O1,O2,CGO>(wb,wo,s1h,s1l,s2h,s2l,wscr,cgp,tk0,tk1,wave,lane);
  } else {
    tp_chunk<D1,D2,D3,3,0,O1,O2,CGO>(wb,wo,s1h,s1l,s2h,s2l,wscr,cgp,tk0,tk1,wave,lane);
    tp_chunk<D1,D2,D3,2,3,O1,O2,CGO>(wb,wo,s1h,s1l,s2h,s2l,wscr,cgp,tk0,tk1,wave,lane);
  }
}

__device__ void tp_uvu_all(const unsigned short* __restrict__ wb, int two,
    const unsigned short* s1h, const unsigned short* s1l,
    const unsigned short* s2h, const unsigned short* s2l,
    unsigned short* dh, unsigned short* dl,
    float* wscr, const float* __restrict__ cgp, int wave, int lane)
{
  const float f192 = 0.07216878364870323f;  // 1/sqrt(192)
  const float f256 = 0.0625f;               // 1/sqrt(256)
  int na = 2*wave, nb = 2*wave+1;
  { // out l0 @0 (fan 192): paths 0,5,10
    float tk0[1]={0.f}, tk1[1]={0.f};
    tp_path<1,1,1,  0,  0,  0>(wb,two+ 0*4096, s1h,s1l,s2h,s2l,wscr,cgp,tk0,tk1,wave,lane);
    tp_path<3,3,1, 64, 64, 69>(wb,two+ 5*4096, s1h,s1l,s2h,s2l,wscr,cgp,tk0,tk1,wave,lane);
    tp_path<5,5,1,256,256,300>(wb,two+10*4096, s1h,s1l,s2h,s2l,wscr,cgp,tk0,tk1,wave,lane);
    store_hl(dh,dl, na*SSTRIDE + lane, tk0[0]*f192);
    store_hl(dh,dl, nb*SSTRIDE + lane, tk1[0]*f192);
  }
  { // out l1 @64 (fan 256): paths 1,4,6,11
    float tk0[3]={0,0,0}, tk1[3]={0,0,0};
    tp_path<1,3,3,  0, 64,  1>(wb,two+ 1*4096, s1h,s1l,s2h,s2l,wscr,cgp,tk0,tk1,wave,lane);
    tp_path<3,1,3, 64,  0, 10>(wb,two+ 4*4096, s1h,s1l,s2h,s2l,wscr,cgp,tk0,tk1,wave,lane);
    tp_path<3,3,3, 64, 64, 78>(wb,two+ 6*4096, s1h,s1l,s2h,s2l,wscr,cgp,tk0,tk1,wave,lane);
    tp_path<5,5,3,256,256,325>(wb,two+11*4096, s1h,s1l,s2h,s2l,wscr,cgp,tk0,tk1,wave,lane);
    #pragma unroll
    for (int k=0;k<3;k++){
      store_hl(dh,dl, na*SSTRIDE + 64 + k*64 + lane, tk0[k]*f256);
      store_hl(dh,dl, nb*SSTRIDE + 64 + k*64 + lane, tk1[k]*f256);
    }
  }
  { // out l2 @256 (fan 256): paths 2,8,9,13
    float tk0[5]={0,0,0,0,0}, tk1[5]={0,0,0,0,0};
    tp_path<1,5,5,  0,256, 19>(wb,two+ 2*4096, s1h,s1l,s2h,s2l,wscr,cgp,tk0,tk1,wave,lane);
    tp_path<5,1,5,256,  0, 44>(wb,two+ 8*4096, s1h,s1l,s2h,s2l,wscr,cgp,tk0,tk1,wave,lane);
    tp_path<5,3,5,256, 64,150>(wb,two+ 9*4096, s1h,s1l,s2h,s2l,wscr,cgp,tk0,tk1,wave,lane);
    tp_path<5,3,5,256,576,150>(wb,two+13*4096, s1h,s1l,s2h,s2l,wscr,cgp,tk0,tk1,wave,lane);
    #pragma unroll
    for (int k=0;k<5;k++){
      store_hl(dh,dl, na*SSTRIDE + 256 + k*64 + lane, tk0[k]*f256);
      store_hl(dh,dl, nb*SSTRIDE + 256 + k*64 + lane, tk1[k]*f256);
    }
  }
  { // out l1b @576 (fan 192): paths 3,7,12
    float tk0[3]={0,0,0}, tk1[3]={0,0,0};
    tp_path<1,3,3,  0,576,  1>(wb,two+ 3*4096, s1h,s1l,s2h,s2l,wscr,cgp,tk0,tk1,wave,lane);
    tp_path<3,3,3, 64, 64, 78>(wb,two+ 7*4096, s1h,s1l,s2h,s2l,wscr,cgp,tk0,tk1,wave,lane);
    tp_path<5,5,3,256,256,325>(wb,two+12*4096, s1h,s1l,s2h,s2l,wscr,cgp,tk0,tk1,wave,lane);
    #pragma unroll
    for (int k=0;k<3;k++){
      store_hl(dh,dl, na*SSTRIDE + 576 + k*64 + lane, tk0[k]*f192);
      store_hl(dh,dl, nb*SSTRIDE + 576 + k*64 + lane, tk1[k]*f192);
    }
  }
}

template<int D3>
__device__ __forceinline__ void wave_reduce_out(float* tk, float* s_out, int n, int lane, int iob){
  #pragma unroll
  for (int k=0;k<D3;k++){
    float v = tk[k];
    v += __shfl_down(v, 32, 64);
    v += __shfl_down(v, 16, 64);
    v += __shfl_down(v,  8, 64);
    v += __shfl_down(v,  4, 64);
    v += __shfl_down(v,  2, 64);
    v += __shfl_down(v,  1, 64);
    if (lane==0) s_out[n*6 + iob + k] = v;
  }
}

// ============================================================================
__global__ __launch_bounds__(NT) void deeprst_main(
    const float* __restrict__ x,
    const float* __restrict__ l1W0, const float* __restrict__ l1W1,
    const float* __restrict__ l1W2, const float* __restrict__ l1b0,
    const float* __restrict__ l2b0, const float* __restrict__ Lb0,
    const unsigned short* __restrict__ wb, const float* __restrict__ cgp,
    float* __restrict__ out)
{
  __shared__ unsigned short sth[3*BUF];   // 74496 B hi plane
  __shared__ unsigned short stl[3*BUF];   // 74496 B lo plane
  __shared__ float s_scr[8*408];          // 13056 B per-wave b scratch (68*6 each)

  const int tid  = threadIdx.x;
  const int lane = tid & 63;
  const int wave = tid >> 6;
  const int n0   = blockIdx.x * TS;
  const float rs8 = 0.3535533905932738f;
  float* wscr = s_scr + wave*408;

  // ---- lin1 (scalar fp32 -> hi/lo), h1 in buffers 0+1 of both planes ----
  for (int idx=tid; idx<TS*128; idx+=NT){
    int n=idx>>7, o=idx&127;
    const float* xp = x + (n0+n)*80;
    float acc=0.f;
    #pragma unroll
    for (int v=0;v<16;v++) acc += xp[v]*l1W0[v*128+o];
    store_hl(sth,stl, n*H1S + o, acc*0.25f + l1b0[o]);
  }
  for (int idx=tid; idx<TS*768; idx+=NT){
    int o=idx&255, i=(idx>>8)%3, n=idx/768;
    const float* xp = x + (n0+n)*80 + 16;
    float acc=0.f;
    #pragma unroll
    for (int v=0;v<8;v++) acc += xp[v*3+i]*l1W1[v*256+o];
    int du = (o<128)? (128 + i*128 + o) : (1152 + i*128 + o-128);
    store_hl(sth,stl, n*H1S + du, acc*rs8);
  }
  for (int idx=tid; idx<TS*640; idx+=NT){
    int o=idx&127, i=(idx>>7)%5, n=idx/640;
    const float* xp = x + (n0+n)*80 + 40;
    float acc=0.f;
    #pragma unroll
    for (int v=0;v<8;v++) acc += xp[v*5+i]*l1W2[v*128+o];
    store_hl(sth,stl, n*H1S + 512 + i*128 + o, acc*rs8);
  }
  __syncthreads();

  // ---- lin2 (MFMA hi/lo): h1 -> buffer 2 ----
  lin2_mfma(wb, l2b0, sth, stl, sth+2*BUF, stl+2*BUF, wave, lane);
  __syncthreads();

  // ---- 3 rounds: split -> tp_uvu (barrier-free) -> linear ----
  int ih = 2, i0 = 0, i1 = 1;
  for (int r=0;r<3;r++){
    unsigned short *hh=sth+ih*BUF, *hl=stl+ih*BUF;
    unsigned short *ah=sth+i0*BUF, *al=stl+i0*BUF;
    unsigned short *bh=sth+i1*BUF, *bl=stl+i1*BUF;
    linL_mfma(wb, OFF_LW0+(3*r  )*4096, OFF_LW1+(3*r  )*16384, OFF_LW2+(3*r  )*4096,
              Lb0+(3*r  )*64, hh, hl, ah, al, wave, lane);
    linL_mfma(wb, OFF_LW0+(3*r+1)*4096, OFF_LW1+(3*r+1)*16384, OFF_LW2+(3*r+1)*4096,
              Lb0+(3*r+1)*64, hh, hl, bh, bl, wave, lane);
    __syncthreads();   // u0,u1 visible; all reads of h done
    tp_uvu_all(wb, OFF_TPW + r*14*4096, ah, al, bh, bl, hh, hl, wscr, cgp, wave, lane);
    __syncthreads();   // ht (in h) visible
    linL_mfma(wb, OFF_LW0+(3*r+2)*4096, OFF_LW1+(3*r+2)*16384, OFF_LW2+(3*r+2)*4096,
              Lb0+(3*r+2)*64, hh, hl, ah, al, wave, lane);
    __syncthreads();   // new h (in u0) visible
    int nh=i0; i0=i1; i1=ih; ih=nh;
  }

  // ---- split4 + fully-connected TP (barrier-free) ----
  unsigned short *hh=sth+ih*BUF, *hl=stl+ih*BUF;
  unsigned short *ah=sth+i0*BUF, *al=stl+i0*BUF;
  unsigned short *bh=sth+i1*BUF, *bl=stl+i1*BUF;
  linL_mfma(wb, OFF_LW0+ 9*4096, OFF_LW1+ 9*16384, OFF_LW2+ 9*4096, Lb0+ 9*64, hh, hl, ah, al, wave, lane);
  linL_mfma(wb, OFF_LW0+10*4096, OFF_LW1+10*16384, OFF_LW2+10*4096, Lb0+10*64, hh, hl, bh, bl, wave, lane);
  __syncthreads();   // u0,u1 visible; reads of hh done (hh becomes s_out)

  float* s_out = (float*)hh;
  int na = 2*wave, nb = 2*wave+1;
  { // out 0e (slot 0): fc paths 0..5
    float tk0[1]={0.f}, tk1[1]={0.f};
    tp_path<1,1,1,  0,  0,  0>(wb,OFF_TP4W+ 0*4096, ah,al,bh,bl,wscr,cgp,tk0,tk1,wave,lane);
    tp_path<3,3,1, 64, 64, 69>(wb,OFF_TP4W+ 1*4096, ah,al,bh,bl,wscr,cgp,tk0,tk1,wave,lane);
    tp_path<3,3,1, 64,576, 69>(wb,OFF_TP4W+ 2*4096, ah,al,bh,bl,wscr,cgp,tk0,tk1,wave,lane);
    tp_path<5,5,1,256,256,300>(wb,OFF_TP4W+ 3*4096, ah,al,bh,bl,wscr,cgp,tk0,tk1,wave,lane);
    tp_path<3,3,1,576, 64, 69>(wb,OFF_TP4W+ 4*4096, ah,al,bh,bl,wscr,cgp,tk0,tk1,wave,lane);
    tp_path<3,3,1,576,576, 69>(wb,OFF_TP4W+ 5*4096, ah,al,bh,bl,wscr,cgp,tk0,tk1,wave,lane);
    wave_reduce_out<1>(tk0, s_out, na, lane, 0);
    wave_reduce_out<1>(tk1, s_out, nb, lane, 0);
  }
  { // out 2e (slots 1..5): fc paths 6..16
    float tk0[5]={0,0,0,0,0}, tk1[5]={0,0,0,0,0};
    tp_path<1,5,5,  0,256, 19>(wb,OFF_TP4W+ 6*4096, ah,al,bh,bl,wscr,cgp,tk0,tk1,wave,lane);
    tp_path<3,3,5, 64, 64,105>(wb,OFF_TP4W+ 7*4096, ah,al,bh,bl,wscr,cgp,tk0,tk1,wave,lane);
    tp_path<3,5,5, 64,256,225>(wb,OFF_TP4W+ 8*4096, ah,al,bh,bl,wscr,cgp,tk0,tk1,wave,lane);
    tp_path<3,3,5, 64,576,105>(wb,OFF_TP4W+ 9*4096, ah,al,bh,bl,wscr,cgp,tk0,tk1,wave,lane);
    tp_path<5,1,5,256,  0, 44>(wb,OFF_TP4W+10*4096, ah,al,bh,bl,wscr,cgp,tk0,tk1,wave,lane);
    tp_path<5,3,5,256, 64,150>(wb,OFF_TP4W+11*4096, ah,al,bh,bl,wscr,cgp,tk0,tk1,wave,lane);
    tp_path<5,5,5,256,256,400>(wb,OFF_TP4W+12*4096, ah,al,bh,bl,wscr,cgp,tk0,tk1,wave,lane);
    tp_path<5,3,5,256,576,150>(wb,OFF_TP4W+13*4096, ah,al,bh,bl,wscr,cgp,tk0,tk1,wave,lane);
    tp_path<3,3,5,576, 64,105>(wb,OFF_TP4W+14*4096, ah,al,bh,bl,wscr,cgp,tk0,tk1,wave,lane);
    tp_path<3,5,5,576,256,225>(wb,OFF_TP4W+15*4096, ah,al,bh,bl,wscr,cgp,tk0,tk1,wave,lane);
    tp_path<3,3,5,576,576,105>(wb,OFF_TP4W+16*4096, ah,al,bh,bl,wscr,cgp,tk0,tk1,wave,lane);
    wave_reduce_out<5>(tk0, s_out, na, lane, 1);
    wave_reduce_out<5>(tk1, s_out, nb, lane, 1);
  }
  __syncthreads();

  if (tid < TS*6){
    int n=tid/6, k=tid%6;
    float sc = (k==0)? (1.0f/sqrtf(24576.0f)) : (1.0f/sqrtf(45056.0f));
    out[(n0+n)*6+k] = s_out[tid]*sc;
  }
}

// ============================================================================
extern "C" void kernel_launch(void* const* d_in, const int* in_sizes, int n_in,
                              void* d_out, int out_size, void* d_ws, size_t ws_size,
                              hipStream_t stream)
{
  (void)n_in; (void)out_size; (void)ws_size;
  const float* x    = (const float*)d_in[0];
  const float* l1W0 = (const float*)d_in[1];
  const float* l1W1 = (const float*)d_in[2];
  const float* l1W2 = (const float*)d_in[3];
  const float* l1b0 = (const float*)d_in[4];
  const float* l2W0 = (const float*)d_in[5];
  const float* l2W1 = (const float*)d_in[6];
  const float* l2W2 = (const float*)d_in[7];
  const float* l2b0 = (const float*)d_in[8];
  const float* LW0  = (const float*)d_in[9];
  const float* LW1  = (const float*)d_in[10];
  const float* LW2  = (const float*)d_in[11];
  const float* Lb0  = (const float*)d_in[12];
  const float* tpw  = (const float*)d_in[13];
  const float* tp4w = (const float*)d_in[14];

  float* cg = (float*)d_ws;                                    // 525 f32 @ ws+0
  unsigned short* wb = (unsigned short*)((char*)d_ws + 4096);  // hi + lo planes
  const int n = in_sizes[0]/80;

  cg_init_kernel<<<1, 576, 0, stream>>>(cg);
  prep_kernel<<<(W_TOT+255)/256, 256, 0, stream>>>(l2W0,l2W1,l2W2,LW0,LW1,LW2,tpw,tp4w,wb);
  deeprst_main<<<n/TS, NT, 0, stream>>>(x,l1W0,l1W1,l1W2,l1b0,l2b0,Lb0,wb,cg,(float*)d_out);
}

// Round 7
// 1961.710 us; speedup vs baseline: 1.0837x; 1.0837x over previous
//
#include <hip/hip_runtime.h>
#include <math.h>

constexpr int TS = 8;      // samples per block
constexpr int NT = 512;    // threads per block (8 waves)
constexpr int SSTRIDE = 776;   // bf16 per sample, HID0 state (768 + 8 pad)
constexpr int H1S = 1544;      // bf16 per sample, HID1 transient (1536 + 8 pad)
constexpr int BUF = TS*SSTRIDE;  // 6208
// HID0 per-sample layout: l0 @0 (64: [u]), l1 @64 (3x64: [i][u]),
// l2 @256 (5x64), l1b @576 (3x64)
// HID1 layout: l0 @0 (128), l1 @128 (3x128), l2 @512 (5x128), l1b @1152 (3x128)

typedef __attribute__((ext_vector_type(8))) short bf16x8;
typedef __attribute__((ext_vector_type(4))) float f32x4;

__device__ inline f32x4 mfma16(bf16x8 a, bf16x8 b, f32x4 c){
  return __builtin_amdgcn_mfma_f32_16x16x32_bf16(a, b, c, 0, 0, 0);
}
__device__ inline unsigned short f2b(float f){
  union { float f; unsigned u; } v; v.f = f;
  return (unsigned short)((v.u + 0x7fffu + ((v.u >> 16) & 1u)) >> 16);
}
__device__ inline float b2f(unsigned short h){
  union { unsigned u; float f; } v; v.u = ((unsigned)h) << 16; return v.f;
}
__device__ inline void store_hl(unsigned short* ph, unsigned short* pl, int idx, float v){
  unsigned short h = f2b(v);
  ph[idx] = h;
  pl[idx] = f2b(v - b2f(h));
}
#define LDFRAG(p) (*(const bf16x8*)(p))

// ws bf16 weight offsets (elements, base = ws+4096B). lo plane at +W_TOT.
constexpr int OFF_L2W0 = 0;        // 64x128 (WT[o][k])
constexpr int OFF_L2W1 = 8192;     // 128x256
constexpr int OFF_L2W2 = 40960;    // 64x128
constexpr int OFF_LW0  = 49152;    // 11 x 64x64
constexpr int OFF_LW1  = 94208;    // 11 x 128x128
constexpr int OFF_LW2  = 274432;   // 11 x 64x64
constexpr int OFF_TPW  = 319488;   // 3x14 x 64x64 ([u][v])
constexpr int OFF_TP4W = 491520;   // 17 x 64x64
constexpr int W_TOT    = 561152;

// ============================================================================
// Clebsch-Gordan init (element-parallel fp64; verified R2-R6)
// offsets: 0:(0,0,0)@0 1:(0,1,1)@1 2:(1,0,1)@10 3:(0,2,2)@19 4:(2,0,2)@44
// 5:(1,1,0)@69 6:(1,1,1)@78 7:(1,1,2)@105 8:(2,1,2)@150 9:(1,2,2)@225
// 10:(2,2,0)@300 11:(2,2,1)@325 12:(2,2,2)@400 ; total 525 floats
// ============================================================================
__device__ inline double dfact(int n){ double r=1.0; for(int i=2;i<=n;i++) r*=(double)i; return r; }
struct dcplx { double x, y; };
__device__ inline dcplx cmul(dcplx a, dcplx b){ return {a.x*b.x-a.y*b.y, a.x*b.y+a.y*b.x}; }

__device__ dcplx Uent(int l, int r, int c){
  double re=0.0, im=0.0;
  double s = 1.0/sqrt(2.0);
  if (r==l && c==l) re = 1.0;
  else if (c>l){ int m=c-l; double sgn=(m&1)?-1.0:1.0;
    if (r==l-m) re = s; else if (r==l+m) re = sgn*s;
  } else if (c<l){ int m=l-c; double sgn=(m&1)?-1.0:1.0;
    if (r==l-m) im = s; else if (r==l+m) im = -sgn*s;
  }
  int lm=l&3; double pr,pi;
  if(lm==0){pr=1;pi=0;} else if(lm==1){pr=0;pi=-1;} else if(lm==2){pr=-1;pi=0;} else {pr=0;pi=1;}
  return { re*pr-im*pi, re*pi+im*pr };
}

__device__ double cg_complex_entry(int l1,int l2,int l3,int m1,int m2){
  int m3=m1+m2;
  if (m3<-l3 || m3>l3) return 0.0;
  double pref = sqrt((double)(2*l3+1)*dfact(l3+l1-l2)*dfact(l3-l1+l2)*dfact(l1+l2-l3)/dfact(l1+l2+l3+1));
  pref *= sqrt(dfact(l3+m3)*dfact(l3-m3)*dfact(l1-m1)*dfact(l1+m1)*dfact(l2-m2)*dfact(l2+m2));
  double s=0.0;
  for(int k=0;k<=l1+l2-l3;k++){
    int a2=l1-m1-k, a3=l2+m2-k, a4=l3-l2+m1+k, a5=l3-l1-m2+k;
    if(a2<0||a3<0||a4<0||a5<0) continue;
    double t=1.0/(dfact(k)*dfact(l1+l2-l3-k)*dfact(a2)*dfact(a3)*dfact(a4)*dfact(a5));
    s += (k&1)? -t : t;
  }
  return pref*s;
}

__global__ void cg_init_kernel(float* cg){
  __shared__ double sKr[525], sKi[525];
  __shared__ double sScale[13];
  __shared__ int    sSel[13];
  const int L1[13]={0,0,1,0,2,1,1,1,2,1,2,2,2};
  const int L2[13]={0,1,0,2,0,1,1,1,1,2,2,2,2};
  const int L3[13]={0,1,1,2,2,0,1,2,2,2,0,1,2};
  const int OFF[14]={0,1,10,19,44,69,78,105,150,225,300,325,400,525};
  const int tid = threadIdx.x;
  int combo=-1, l1=0,l2=0,l3=0;
  if (tid < 525){
    combo=12;
    for(int i=0;i<12;i++) if (tid < OFF[i+1]) { combo=i; break; }
    l1=L1[combo]; l2=L2[combo]; l3=L3[combo];
    int d2=2*l2+1, d3=2*l3+1;
    int e = tid - OFF[combo];
    int a = e/(d2*d3), b=(e/d3)%d2, cc=e%d3;
    double kr=0.0, ki=0.0;
    for(int m=0;m<2*l1+1;m++) for(int n=0;n<d2;n++){
      int m3 = (m-l1)+(n-l2);
      if (m3<-l3||m3>l3) continue;
      double cv = cg_complex_entry(l1,l2,l3,m-l1,n-l2);
      if (cv==0.0) continue;
      dcplx u1=Uent(l1,m,a), u2=Uent(l2,n,b), u3=Uent(l3,m3+l3,cc);
      u3.y = -u3.y;
      dcplx t = cmul(cmul(u1,u2),u3);
      kr += t.x*cv; ki += t.y*cv;
    }
    sKr[tid]=kr; sKi[tid]=ki;
  }
  __syncthreads();
  if (tid < 13){
    int sz = OFF[tid+1]-OFF[tid];
    double nr=0,ni=0;
    for(int i=0;i<sz;i++){ double r=sKr[OFF[tid]+i], im=sKi[OFF[tid]+i]; nr+=r*r; ni+=im*im; }
    int sel = (nr>=ni)? 0 : 1;
    sSel[tid]=sel;
    sScale[tid] = sqrt((double)(2*L3[tid]+1))/sqrt(sel? ni : nr);
  }
  __syncthreads();
  if (tid < 525){
    double v = sSel[combo]? sKi[tid] : sKr[tid];
    cg[tid] = (float)(v*sScale[combo]);
  }
}

// ============================================================================
// Weight prep: fp32 -> bf16 hi/lo planes. Linear weights transposed WT[o][k];
// TP weights [u][v].
// ============================================================================
__global__ void prep_kernel(const float* __restrict__ l2W0, const float* __restrict__ l2W1,
                            const float* __restrict__ l2W2, const float* __restrict__ LW0,
                            const float* __restrict__ LW1, const float* __restrict__ LW2,
                            const float* __restrict__ tpw, const float* __restrict__ tp4w,
                            unsigned short* __restrict__ wb){
  int i = blockIdx.x*256 + threadIdx.x;
  if (i >= W_TOT) return;
  float v;
  if (i < 8192){ int o=i>>7, k=i&127; v = l2W0[k*64+o]; }
  else if (i < 40960){ int j=i-8192; int o=j>>8, k=j&255; v = l2W1[k*128+o]; }
  else if (i < 49152){ int j=i-40960; int o=j>>7, k=j&127; v = l2W2[k*64+o]; }
  else if (i < 94208){ int j=i-49152; int li=j>>12, r=j&4095, o=r>>6, k=r&63; v = LW0[li*4096+k*64+o]; }
  else if (i < 274432){ int j=i-94208; int li=j>>14, r=j&16383, o=r>>7, k=r&127; v = LW1[li*16384+k*128+o]; }
  else if (i < 319488){ int j=i-274432; int li=j>>12, r=j&4095, o=r>>6, k=r&63; v = LW2[li*4096+k*64+o]; }
  else if (i < 491520){ v = tpw[i-319488]; }
  else { v = tp4w[i-491520]; }
  unsigned short h = f2b(v);
  wb[i] = h;
  wb[W_TOT + i] = f2b(v - b2f(h));
}

// ============================================================================
// MFMA linear HID0->HID0 (hi/lo). Jobs: 0..3 l0 | 4..11 l1 | 12..15 l2.
// M-dim: samples occupy rows 0..7; A rows 8..15 duplicate (l16&7), D rows
// 8..15 discarded (quad<2 store guard).
// ============================================================================
__device__ void linL_mfma(const unsigned short* __restrict__ wb, int o0, int o1, int o2,
                          const float* __restrict__ b0,
                          const unsigned short* sh, const unsigned short* sl,
                          unsigned short* dh, unsigned short* dl, int wave, int lane)
{
  const float rs128 = 0.08838834764831845f;
  int l16 = lane & 15, quad = lane >> 4;
  int abase = (l16 & 7) * SSTRIDE;
  for (int job = wave; job < 16; job += 8){
    if (job < 4){                 // l0: K=64, /8 + bias
      int col = job*16 + l16;
      f32x4 a0 = {0,0,0,0}, a1 = {0,0,0,0};
      #pragma unroll
      for (int ks=0; ks<2; ks++){
        int so = abase + ks*32 + quad*8;
        bf16x8 xh = LDFRAG(sh+so), xl = LDFRAG(sl+so);
        int wo = o0 + col*64 + ks*32 + quad*8;
        bf16x8 wh = LDFRAG(wb+wo), wl = LDFRAG(wb+W_TOT+wo);
        a0 = mfma16(xh,wh,a0); a1 = mfma16(xh,wl,a1); a1 = mfma16(xl,wh,a1);
      }
      float bias = b0[col];
      if (quad < 2){
        #pragma unroll
        for (int r=0;r<4;r++)
          store_hl(dh,dl,(quad*4+r)*SSTRIDE + col, (a0[r]+a1[r])*0.125f + bias);
      }
    } else if (job < 12){         // l1: K=128 (l1|l1b), /sqrt(128)
      int nt = job-4; int col = nt*16 + l16;
      #pragma unroll
      for (int i=0;i<3;i++){
        f32x4 a0 = {0,0,0,0}, a1 = {0,0,0,0};
        #pragma unroll
        for (int ks=0; ks<4; ks++){
          int ka = ks*32 + quad*8;
          int so = abase + ((ka < 64) ? (64 + i*64 + ka) : (576 + i*64 + ka - 64));
          bf16x8 xh = LDFRAG(sh+so), xl = LDFRAG(sl+so);
          int wo = o1 + col*128 + ka;
          bf16x8 wh = LDFRAG(wb+wo), wl = LDFRAG(wb+W_TOT+wo);
          a0 = mfma16(xh,wh,a0); a1 = mfma16(xh,wl,a1); a1 = mfma16(xl,wh,a1);
        }
        int dof = (col < 64) ? (64 + i*64 + col) : (576 + i*64 + col - 64);
        if (quad < 2){
          #pragma unroll
          for (int r=0;r<4;r++)
            store_hl(dh,dl,(quad*4+r)*SSTRIDE + dof, (a0[r]+a1[r])*rs128);
        }
      }
    } else {                      // l2: K=64, /8
      int nt = job-12; int col = nt*16 + l16;
      #pragma unroll
      for (int i=0;i<5;i++){
        f32x4 a0 = {0,0,0,0}, a1 = {0,0,0,0};
        #pragma unroll
        for (int ks=0; ks<2; ks++){
          int so = abase + 256 + i*64 + ks*32 + quad*8;
          bf16x8 xh = LDFRAG(sh+so), xl = LDFRAG(sl+so);
          int wo = o2 + col*64 + ks*32 + quad*8;
          bf16x8 wh = LDFRAG(wb+wo), wl = LDFRAG(wb+W_TOT+wo);
          a0 = mfma16(xh,wh,a0); a1 = mfma16(xh,wl,a1); a1 = mfma16(xl,wh,a1);
        }
        if (quad < 2){
          #pragma unroll
          for (int r=0;r<4;r++)
            store_hl(dh,dl,(quad*4+r)*SSTRIDE + 256 + i*64 + col, (a0[r]+a1[r])*0.125f);
        }
      }
    }
  }
}

// lin2: HID1 -> HID0 (K=128/256/128), hi/lo
__device__ void lin2_mfma(const unsigned short* __restrict__ wb,
                          const float* __restrict__ b0,
                          const unsigned short* h1h, const unsigned short* h1l,
                          unsigned short* dh, unsigned short* dl, int wave, int lane)
{
  const float rs128 = 0.08838834764831845f;
  int l16 = lane & 15, quad = lane >> 4;
  int abase = (l16 & 7) * H1S;
  for (int job = wave; job < 16; job += 8){
    if (job < 4){                 // l0: K=128
      int col = job*16 + l16;
      f32x4 a0 = {0,0,0,0}, a1 = {0,0,0,0};
      #pragma unroll
      for (int ks=0; ks<4; ks++){
        int so = abase + ks*32 + quad*8;
        bf16x8 xh = LDFRAG(h1h+so), xl = LDFRAG(h1l+so);
        int wo = OFF_L2W0 + col*128 + ks*32 + quad*8;
        bf16x8 wh = LDFRAG(wb+wo), wl = LDFRAG(wb+W_TOT+wo);
        a0 = mfma16(xh,wh,a0); a1 = mfma16(xh,wl,a1); a1 = mfma16(xl,wh,a1);
      }
      float bias = b0[col];
      if (quad < 2){
        #pragma unroll
        for (int r=0;r<4;r++)
          store_hl(dh,dl,(quad*4+r)*SSTRIDE + col, (a0[r]+a1[r])*rs128 + bias);
      }
    } else if (job < 12){         // l1: K=256, /16
      int nt = job-4; int col = nt*16 + l16;
      #pragma unroll
      for (int i=0;i<3;i++){
        f32x4 a0 = {0,0,0,0}, a1 = {0,0,0,0};
        #pragma unroll
        for (int ks=0; ks<8; ks++){
          int ka = ks*32 + quad*8;
          int so = abase + ((ka < 128) ? (128 + i*128 + ka) : (1152 + i*128 + ka - 128));
          bf16x8 xh = LDFRAG(h1h+so), xl = LDFRAG(h1l+so);
          int wo = OFF_L2W1 + col*256 + ka;
          bf16x8 wh = LDFRAG(wb+wo), wl = LDFRAG(wb+W_TOT+wo);
          a0 = mfma16(xh,wh,a0); a1 = mfma16(xh,wl,a1); a1 = mfma16(xl,wh,a1);
        }
        int dof = (col < 64) ? (64 + i*64 + col) : (576 + i*64 + col - 64);
        if (quad < 2){
          #pragma unroll
          for (int r=0;r<4;r++)
            store_hl(dh,dl,(quad*4+r)*SSTRIDE + dof, (a0[r]+a1[r])*0.0625f);
        }
      }
    } else {                      // l2: K=128
      int nt = job-12; int col = nt*16 + l16;
      #pragma unroll
      for (int i=0;i<5;i++){
        f32x4 a0 = {0,0,0,0}, a1 = {0,0,0,0};
        #pragma unroll
        for (int ks=0; ks<4; ks++){
          int so = abase + 512 + i*128 + ks*32 + quad*8;
          bf16x8 xh = LDFRAG(h1h+so), xl = LDFRAG(h1l+so);
          int wo = OFF_L2W2 + col*128 + ks*32 + quad*8;
          bf16x8 wh = LDFRAG(wb+wo), wl = LDFRAG(wb+W_TOT+wo);
          a0 = mfma16(xh,wh,a0); a1 = mfma16(xh,wl,a1); a1 = mfma16(xl,wh,a1);
        }
        if (quad < 2){
          #pragma unroll
          for (int r=0;r<4;r++)
            store_hl(dh,dl,(quad*4+r)*SSTRIDE + 256 + i*64 + col, (a0[r]+a1[r])*rs128);
        }
      }
    }
  }
}

// ============================================================================
// Block-level TP chunk (R5 structure, TS=8): stage b for JC (<=3) j-columns
// via 3-MFMA hi/lo into shared b_s, then scalar CG partial contraction
// (one sample per wave, n=wave). CG coeffs from global (uniform s_load).
// ============================================================================
template<int D1,int D2,int D3,int JC,int J0,int O1,int O2,int CGO>
__device__ __forceinline__ void tp_chunk(
    const unsigned short* __restrict__ wb, int wo,
    const unsigned short* s1h, const unsigned short* s1l,
    const unsigned short* s2h, const unsigned short* s2l,
    float* b_s, const float* __restrict__ cgp,
    float* tk, int wave, int lane)
{
  __syncthreads();               // prior b_s readers / state writers done
  {
    int l16 = lane & 15, quad = lane >> 4;
    int n = l16 & 7;             // B cols 8..15 duplicate samples, discarded
    for (int job = wave; job < 4*JC; job += 8){
      int mt = job & 3, jj = job >> 2;
      int j = J0 + jj;
      f32x4 a0 = {0,0,0,0}, a1 = {0,0,0,0};
      #pragma unroll
      for (int ks=0; ks<2; ks++){
        int wofs = wo + (mt*16 + l16)*64 + ks*32 + quad*8;
        bf16x8 wh = LDFRAG(wb + wofs);
        bf16x8 wl = LDFRAG(wb + W_TOT + wofs);
        int sofs = n*SSTRIDE + O2 + j*64 + ks*32 + quad*8;
        bf16x8 xh = LDFRAG(s2h + sofs);
        bf16x8 xl = LDFRAG(s2l + sofs);
        a0 = mfma16(wh,xh,a0); a1 = mfma16(wh,xl,a1); a1 = mfma16(wl,xh,a1);
      }
      if (l16 < 8){
        f32x4 s;
        #pragma unroll
        for (int r=0;r<4;r++) s[r] = a0[r]+a1[r];
        *(f32x4*)&b_s[(jj*8 + n)*68 + mt*16 + quad*4] = s;  // [j,n][u], 68-pad
      }
    }
  }
  __syncthreads();
  {
    int n = wave, u = lane;
    float x1v[D1], bv[JC];
    #pragma unroll
    for (int i=0;i<D1;i++){
      int o = n*SSTRIDE + O1 + i*64 + u;
      x1v[i] = b2f(s1h[o]) + b2f(s1l[o]);
    }
    #pragma unroll
    for (int jj=0;jj<JC;jj++) bv[jj] = b_s[(jj*8 + n)*68 + u];
    #pragma unroll
    for (int i=0;i<D1;i++){
      #pragma unroll
      for (int jj=0;jj<JC;jj++){
        float pr = x1v[i]*bv[jj];
        #pragma unroll
        for (int k=0;k<D3;k++) tk[k] += pr*cgp[CGO + (i*D2 + J0+jj)*D3 + k];
      }
    }
  }
}

template<int D1,int D2,int D3,int O1,int O2,int CGO>
__device__ __forceinline__ void tp_path(
    const unsigned short* __restrict__ wb, int wo,
    const unsigned short* s1h, const unsigned short* s1l,
    const unsigned short* s2h, const unsigned short* s2l,
    float* b_s, const float* __restrict__ cgp,
    float* tk, int wave, int lane)
{
  if constexpr (D2 <= 3){
    tp_chunk<D1,D2,D3,D2,0,O1,O2,CGO>(wb,wo,s1h,s1l,s2h,s2l,b_s,cgp,tk,wave,lane);
  } else {
    tp_chunk<D1,D2,D3,3,0,O1,O2,CGO>(wb,wo,s1h,s1l,s2h,s2l,b_s,cgp,tk,wave,lane);
    tp_chunk<D1,D2,D3,2,3,O1,O2,CGO>(wb,wo,s1h,s1l,s2h,s2l,b_s,cgp,tk,wave,lane);
  }
}

__device__ void tp_uvu_all(const unsigned short* __restrict__ wb, int two,
    const unsigned short* s1h, const unsigned short* s1l,
    const unsigned short* s2h, const unsigned short* s2l,
    unsigned short* dh, unsigned short* dl,
    float* b_s, const float* __restrict__ cgp, int wave, int lane)
{
  const float f192 = 0.07216878364870323f;  // 1/sqrt(192)
  const float f256 = 0.0625f;               // 1/sqrt(256)
  int n = wave;
  { // out l0 @0 (fan 192): paths 0,5,10
    float tk[1]={0.f};
    tp_path<1,1,1,  0,  0,  0>(wb,two+ 0*4096, s1h,s1l,s2h,s2l,b_s,cgp,tk,wave,lane);
    tp_path<3,3,1, 64, 64, 69>(wb,two+ 5*4096, s1h,s1l,s2h,s2l,b_s,cgp,tk,wave,lane);
    tp_path<5,5,1,256,256,300>(wb,two+10*4096, s1h,s1l,s2h,s2l,b_s,cgp,tk,wave,lane);
    store_hl(dh,dl, n*SSTRIDE + lane, tk[0]*f192);
  }
  { // out l1 @64 (fan 256): paths 1,4,6,11
    float tk[3]={0,0,0};
    tp_path<1,3,3,  0, 64,  1>(wb,two+ 1*4096, s1h,s1l,s2h,s2l,b_s,cgp,tk,wave,lane);
    tp_path<3,1,3, 64,  0, 10>(wb,two+ 4*4096, s1h,s1l,s2h,s2l,b_s,cgp,tk,wave,lane);
    tp_path<3,3,3, 64, 64, 78>(wb,two+ 6*4096, s1h,s1l,s2h,s2l,b_s,cgp,tk,wave,lane);
    tp_path<5,5,3,256,256,325>(wb,two+11*4096, s1h,s1l,s2h,s2l,b_s,cgp,tk,wave,lane);
    #pragma unroll
    for (int k=0;k<3;k++)
      store_hl(dh,dl, n*SSTRIDE + 64 + k*64 + lane, tk[k]*f256);
  }
  { // out l2 @256 (fan 256): paths 2,8,9,13
    float tk[5]={0,0,0,0,0};
    tp_path<1,5,5,  0,256, 19>(wb,two+ 2*4096, s1h,s1l,s2h,s2l,b_s,cgp,tk,wave,lane);
    tp_path<5,1,5,256,  0, 44>(wb,two+ 8*4096, s1h,s1l,s2h,s2l,b_s,cgp,tk,wave,lane);
    tp_path<5,3,5,256, 64,150>(wb,two+ 9*4096, s1h,s1l,s2h,s2l,b_s,cgp,tk,wave,lane);
    tp_path<5,3,5,256,576,150>(wb,two+13*4096, s1h,s1l,s2h,s2l,b_s,cgp,tk,wave,lane);
    #pragma unroll
    for (int k=0;k<5;k++)
      store_hl(dh,dl, n*SSTRIDE + 256 + k*64 + lane, tk[k]*f256);
  }
  { // out l1b @576 (fan 192): paths 3,7,12
    float tk[3]={0,0,0};
    tp_path<1,3,3,  0,576,  1>(wb,two+ 3*4096, s1h,s1l,s2h,s2l,b_s,cgp,tk,wave,lane);
    tp_path<3,3,3, 64, 64, 78>(wb,two+ 7*4096, s1h,s1l,s2h,s2l,b_s,cgp,tk,wave,lane);
    tp_path<5,5,3,256,256,325>(wb,two+12*4096, s1h,s1l,s2h,s2l,b_s,cgp,tk,wave,lane);
    #pragma unroll
    for (int k=0;k<3;k++)
      store_hl(dh,dl, n*SSTRIDE + 576 + k*64 + lane, tk[k]*f192);
  }
}

template<int D3>
__device__ __forceinline__ void wave_reduce_out(float* tk, float* s_out, int n, int lane, int iob){
  #pragma unroll
  for (int k=0;k<D3;k++){
    float v = tk[k];
    v += __shfl_down(v, 32, 64);
    v += __shfl_down(v, 16, 64);
    v += __shfl_down(v,  8, 64);
    v += __shfl_down(v,  4, 64);
    v += __shfl_down(v,  2, 64);
    v += __shfl_down(v,  1, 64);
    if (lane==0) s_out[n*6 + iob + k] = v;
  }
}

// ============================================================================
__global__ __launch_bounds__(NT) void deeprst_main(
    const float* __restrict__ x,
    const float* __restrict__ l1W0, const float* __restrict__ l1W1,
    const float* __restrict__ l1W2, const float* __restrict__ l1b0,
    const float* __restrict__ l2b0, const float* __restrict__ Lb0,
    const unsigned short* __restrict__ wb, const float* __restrict__ cgp,
    float* __restrict__ out)
{
  __shared__ unsigned short sth[3*BUF];   // 37248 B hi plane
  __shared__ unsigned short stl[3*BUF];   // 37248 B lo plane
  __shared__ float b_s[24*68];            // 6528 B  (total 81024 B -> 2 blocks/CU)

  const int tid  = threadIdx.x;
  const int lane = tid & 63;
  const int wave = tid >> 6;
  const int n0   = blockIdx.x * TS;
  const float rs8 = 0.3535533905932738f;

  // ---- lin1 (scalar fp32 -> hi/lo), h1 in buffers 0+1 of both planes ----
  for (int idx=tid; idx<TS*128; idx+=NT){
    int n=idx>>7, o=idx&127;
    const float* xp = x + (n0+n)*80;
    float acc=0.f;
    #pragma unroll
    for (int v=0;v<16;v++) acc += xp[v]*l1W0[v*128+o];
    store_hl(sth,stl, n*H1S + o, acc*0.25f + l1b0[o]);
  }
  for (int idx=tid; idx<TS*768; idx+=NT){
    int o=idx&255, i=(idx>>8)%3, n=idx/768;
    const float* xp = x + (n0+n)*80 + 16;
    float acc=0.f;
    #pragma unroll
    for (int v=0;v<8;v++) acc += xp[v*3+i]*l1W1[v*256+o];
    int du = (o<128)? (128 + i*128 + o) : (1152 + i*128 + o-128);
    store_hl(sth,stl, n*H1S + du, acc*rs8);
  }
  for (int idx=tid; idx<TS*640; idx+=NT){
    int o=idx&127, i=(idx>>7)%5, n=idx/640;
    const float* xp = x + (n0+n)*80 + 40;
    float acc=0.f;
    #pragma unroll
    for (int v=0;v<8;v++) acc += xp[v*5+i]*l1W2[v*128+o];
    store_hl(sth,stl, n*H1S + 512 + i*128 + o, acc*rs8);
  }
  __syncthreads();

  // ---- lin2 (MFMA hi/lo): h1 -> buffer 2 ----
  lin2_mfma(wb, l2b0, sth, stl, sth+2*BUF, stl+2*BUF, wave, lane);
  __syncthreads();

  // ---- 3 rounds: split -> tp_uvu -> linear ----
  int ih = 2, i0 = 0, i1 = 1;
  for (int r=0;r<3;r++){
    unsigned short *hh=sth+ih*BUF, *hl=stl+ih*BUF;
    unsigned short *ah=sth+i0*BUF, *al=stl+i0*BUF;
    unsigned short *bh=sth+i1*BUF, *bl=stl+i1*BUF;
    linL_mfma(wb, OFF_LW0+(3*r  )*4096, OFF_LW1+(3*r  )*16384, OFF_LW2+(3*r  )*4096,
              Lb0+(3*r  )*64, hh, hl, ah, al, wave, lane);
    linL_mfma(wb, OFF_LW0+(3*r+1)*4096, OFF_LW1+(3*r+1)*16384, OFF_LW2+(3*r+1)*4096,
              Lb0+(3*r+1)*64, hh, hl, bh, bl, wave, lane);
    // tp_chunk's leading barrier orders lin writes before TP reads
    tp_uvu_all(wb, OFF_TPW + r*14*4096, ah, al, bh, bl, hh, hl, b_s, cgp, wave, lane);
    __syncthreads();   // ht (in h) visible
    linL_mfma(wb, OFF_LW0+(3*r+2)*4096, OFF_LW1+(3*r+2)*16384, OFF_LW2+(3*r+2)*4096,
              Lb0+(3*r+2)*64, hh, hl, ah, al, wave, lane);
    __syncthreads();   // new h (in u0) visible
    int nh=i0; i0=i1; i1=ih; ih=nh;
  }

  // ---- split4 + fully-connected TP ----
  unsigned short *hh=sth+ih*BUF, *hl=stl+ih*BUF;
  unsigned short *ah=sth+i0*BUF, *al=stl+i0*BUF;
  unsigned short *bh=sth+i1*BUF, *bl=stl+i1*BUF;
  linL_mfma(wb, OFF_LW0+ 9*4096, OFF_LW1+ 9*16384, OFF_LW2+ 9*4096, Lb0+ 9*64, hh, hl, ah, al, wave, lane);
  linL_mfma(wb, OFF_LW0+10*4096, OFF_LW1+10*16384, OFF_LW2+10*4096, Lb0+10*64, hh, hl, bh, bl, wave, lane);

  float* s_out = (float*)hh;   // h buffer dead after split4 linears (reads fenced
                               // by the first tp_chunk barrier below)
  { // out 0e (slot 0): fc paths 0..5
    float tk[1]={0.f};
    tp_path<1,1,1,  0,  0,  0>(wb,OFF_TP4W+ 0*4096, ah,al,bh,bl,b_s,cgp,tk,wave,lane);
    tp_path<3,3,1, 64, 64, 69>(wb,OFF_TP4W+ 1*4096, ah,al,bh,bl,b_s,cgp,tk,wave,lane);
    tp_path<3,3,1, 64,576, 69>(wb,OFF_TP4W+ 2*4096, ah,al,bh,bl,b_s,cgp,tk,wave,lane);
    tp_path<5,5,1,256,256,300>(wb,OFF_TP4W+ 3*4096, ah,al,bh,bl,b_s,cgp,tk,wave,lane);
    tp_path<3,3,1,576, 64, 69>(wb,OFF_TP4W+ 4*4096, ah,al,bh,bl,b_s,cgp,tk,wave,lane);
    tp_path<3,3,1,576,576, 69>(wb,OFF_TP4W+ 5*4096, ah,al,bh,bl,b_s,cgp,tk,wave,lane);
    wave_reduce_out<1>(tk, s_out, wave, lane, 0);
  }
  { // out 2e (slots 1..5): fc paths 6..16
    float tk[5]={0,0,0,0,0};
    tp_path<1,5,5,  0,256, 19>(wb,OFF_TP4W+ 6*4096, ah,al,bh,bl,b_s,cgp,tk,wave,lane);
    tp_path<3,3,5, 64, 64,105>(wb,OFF_TP4W+ 7*4096, ah,al,bh,bl,b_s,cgp,tk,wave,lane);
    tp_path<3,5,5, 64,256,225>(wb,OFF_TP4W+ 8*4096, ah,al,bh,bl,b_s,cgp,tk,wave,lane);
    tp_path<3,3,5, 64,576,105>(wb,OFF_TP4W+ 9*4096, ah,al,bh,bl,b_s,cgp,tk,wave,lane);
    tp_path<5,1,5,256,  0, 44>(wb,OFF_TP4W+10*4096, ah,al,bh,bl,b_s,cgp,tk,wave,lane);
    tp_path<5,3,5,256, 64,150>(wb,OFF_TP4W+11*4096, ah,al,bh,bl,b_s,cgp,tk,wave,lane);
    tp_path<5,5,5,256,256,400>(wb,OFF_TP4W+12*4096, ah,al,bh,bl,b_s,cgp,tk,wave,lane);
    tp_path<5,3,5,256,576,150>(wb,OFF_TP4W+13*4096, ah,al,bh,bl,b_s,cgp,tk,wave,lane);
    tp_path<3,3,5,576, 64,105>(wb,OFF_TP4W+14*4096, ah,al,bh,bl,b_s,cgp,tk,wave,lane);
    tp_path<3,5,5,576,256,225>(wb,OFF_TP4W+15*4096, ah,al,bh,bl,b_s,cgp,tk,wave,lane);
    tp_path<3,3,5,576,576,105>(wb,OFF_TP4W+16*4096, ah,al,bh,bl,b_s,cgp,tk,wave,lane);
    wave_reduce_out<5>(tk, s_out, wave, lane, 1);
  }
  __syncthreads();

  if (tid < TS*6){
    int n=tid/6, k=tid%6;
    float sc = (k==0)? (1.0f/sqrtf(24576.0f)) : (1.0f/sqrtf(45056.0f));
    out[(n0+n)*6+k] = s_out[tid]*sc;
  }
}

// ============================================================================
extern "C" void kernel_launch(void* const* d_in, const int* in_sizes, int n_in,
                              void* d_out, int out_size, void* d_ws, size_t ws_size,
                              hipStream_t stream)
{
  (void)n_in; (void)out_size; (void)ws_size;
  const float* x    = (const float*)d_in[0];
  const float* l1W0 = (const float*)d_in[1];
  const float* l1W1 = (const float*)d_in[2];
  const float* l1W2 = (const float*)d_in[3];
  const float* l1b0 = (const float*)d_in[4];
  const float* l2W0 = (const float*)d_in[5];
  const float* l2W1 = (const float*)d_in[6];
  const float* l2W2 = (const float*)d_in[7];
  const float* l2b0 = (const float*)d_in[8];
  const float* LW0  = (const float*)d_in[9];
  const float* LW1  = (const float*)d_in[10];
  const float* LW2  = (const float*)d_in[11];
  const float* Lb0  = (const float*)d_in[12];
  const float* tpw  = (const float*)d_in[13];
  const float* tp4w = (const float*)d_in[14];

  float* cg = (float*)d_ws;                                    // 525 f32 @ ws+0
  unsigned short* wb = (unsigned short*)((char*)d_ws + 4096);  // hi + lo planes
  const int n = in_sizes[0]/80;

  cg_init_kernel<<<1, 576, 0, stream>>>(cg);
  prep_kernel<<<(W_TOT+255)/256, 256, 0, stream>>>(l2W0,l2W1,l2W2,LW0,LW1,LW2,tpw,tp4w,wb);
  deeprst_main<<<n/TS, NT, 0, stream>>>(x,l1W0,l1W1,l1W2,l1b0,l2b0,Lb0,wb,cg,(float*)d_out);
}

// Round 8
// 1621.610 us; speedup vs baseline: 1.3110x; 1.2097x over previous
//
#include <hip/hip_runtime.h>
#include <math.h>

// Global state layout (per chunk of CS samples, sample-major, stride 768):
// HID0 per-sample: l0 @0 (64 [u]), l1 @64 (3x64 [i][u]), l2 @256 (5x64), l1b @576 (3x64)
// HID1 (h1) stride 1536: l0 @0 (128), l1 @128 (3x128), l2 @512 (5x128), l1b @1152 (3x128)

typedef __attribute__((ext_vector_type(8))) short bf16x8;
typedef __attribute__((ext_vector_type(4))) float f32x4;
typedef __attribute__((ext_vector_type(4))) unsigned short u16x4;

__device__ inline f32x4 mfma16(bf16x8 a, bf16x8 b, f32x4 c){
  return __builtin_amdgcn_mfma_f32_16x16x32_bf16(a, b, c, 0, 0, 0);
}
__device__ inline unsigned short f2b(float f){
  union { float f; unsigned u; } v; v.f = f;
  return (unsigned short)((v.u + 0x7fffu + ((v.u >> 16) & 1u)) >> 16);
}
__device__ inline float b2f(unsigned short h){
  union { unsigned u; float f; } v; v.u = ((unsigned)h) << 16; return v.f;
}
__device__ inline void store_hl(unsigned short* ph, unsigned short* pl, int idx, float v){
  unsigned short h = f2b(v);
  ph[idx] = h;
  pl[idx] = f2b(v - b2f(h));
}
#define LDFRAG(p) (*(const bf16x8*)(p))

// ws bf16 weight offsets (elements, base = ws+4096B). lo plane at +W_TOT.
constexpr int OFF_L2W0 = 0;        // 64x128 (WT[o][k])
constexpr int OFF_L2W1 = 8192;     // 128x256
constexpr int OFF_L2W2 = 40960;    // 64x128
constexpr int OFF_LW0  = 49152;    // 11 x 64x64
constexpr int OFF_LW1  = 94208;    // 11 x 128x128
constexpr int OFF_LW2  = 274432;   // 11 x 64x64
constexpr int OFF_TPW  = 319488;   // 3x14 x 64x64 ([u][v])
constexpr int OFF_TP4W = 491520;   // 17 x 64x64
constexpr int W_TOT    = 561152;

// ============================================================================
// Clebsch-Gordan init (element-parallel fp64; verified R2-R7)
// offsets: 0:(0,0,0)@0 1:(0,1,1)@1 2:(1,0,1)@10 3:(0,2,2)@19 4:(2,0,2)@44
// 5:(1,1,0)@69 6:(1,1,1)@78 7:(1,1,2)@105 8:(2,1,2)@150 9:(1,2,2)@225
// 10:(2,2,0)@300 11:(2,2,1)@325 12:(2,2,2)@400 ; total 525 floats
// ============================================================================
__device__ inline double dfact(int n){ double r=1.0; for(int i=2;i<=n;i++) r*=(double)i; return r; }
struct dcplx { double x, y; };
__device__ inline dcplx cmul(dcplx a, dcplx b){ return {a.x*b.x-a.y*b.y, a.x*b.y+a.y*b.x}; }

__device__ dcplx Uent(int l, int r, int c){
  double re=0.0, im=0.0;
  double s = 1.0/sqrt(2.0);
  if (r==l && c==l) re = 1.0;
  else if (c>l){ int m=c-l; double sgn=(m&1)?-1.0:1.0;
    if (r==l-m) re = s; else if (r==l+m) re = sgn*s;
  } else if (c<l){ int m=l-c; double sgn=(m&1)?-1.0:1.0;
    if (r==l-m) im = s; else if (r==l+m) im = -sgn*s;
  }
  int lm=l&3; double pr,pi;
  if(lm==0){pr=1;pi=0;} else if(lm==1){pr=0;pi=-1;} else if(lm==2){pr=-1;pi=0;} else {pr=0;pi=1;}
  return { re*pr-im*pi, re*pi+im*pr };
}

__device__ double cg_complex_entry(int l1,int l2,int l3,int m1,int m2){
  int m3=m1+m2;
  if (m3<-l3 || m3>l3) return 0.0;
  double pref = sqrt((double)(2*l3+1)*dfact(l3+l1-l2)*dfact(l3-l1+l2)*dfact(l1+l2-l3)/dfact(l1+l2+l3+1));
  pref *= sqrt(dfact(l3+m3)*dfact(l3-m3)*dfact(l1-m1)*dfact(l1+m1)*dfact(l2-m2)*dfact(l2+m2));
  double s=0.0;
  for(int k=0;k<=l1+l2-l3;k++){
    int a2=l1-m1-k, a3=l2+m2-k, a4=l3-l2+m1+k, a5=l3-l1-m2+k;
    if(a2<0||a3<0||a4<0||a5<0) continue;
    double t=1.0/(dfact(k)*dfact(l1+l2-l3-k)*dfact(a2)*dfact(a3)*dfact(a4)*dfact(a5));
    s += (k&1)? -t : t;
  }
  return pref*s;
}

__global__ void cg_init_kernel(float* cg){
  __shared__ double sKr[525], sKi[525];
  __shared__ double sScale[13];
  __shared__ int    sSel[13];
  const int L1[13]={0,0,1,0,2,1,1,1,2,1,2,2,2};
  const int L2[13]={0,1,0,2,0,1,1,1,1,2,2,2,2};
  const int L3[13]={0,1,1,2,2,0,1,2,2,2,0,1,2};
  const int OFF[14]={0,1,10,19,44,69,78,105,150,225,300,325,400,525};
  const int tid = threadIdx.x;
  int combo=-1, l1=0,l2=0,l3=0;
  if (tid < 525){
    combo=12;
    for(int i=0;i<12;i++) if (tid < OFF[i+1]) { combo=i; break; }
    l1=L1[combo]; l2=L2[combo]; l3=L3[combo];
    int d2=2*l2+1, d3=2*l3+1;
    int e = tid - OFF[combo];
    int a = e/(d2*d3), b=(e/d3)%d2, cc=e%d3;
    double kr=0.0, ki=0.0;
    for(int m=0;m<2*l1+1;m++) for(int n=0;n<d2;n++){
      int m3 = (m-l1)+(n-l2);
      if (m3<-l3||m3>l3) continue;
      double cv = cg_complex_entry(l1,l2,l3,m-l1,n-l2);
      if (cv==0.0) continue;
      dcplx u1=Uent(l1,m,a), u2=Uent(l2,n,b), u3=Uent(l3,m3+l3,cc);
      u3.y = -u3.y;
      dcplx t = cmul(cmul(u1,u2),u3);
      kr += t.x*cv; ki += t.y*cv;
    }
    sKr[tid]=kr; sKi[tid]=ki;
  }
  __syncthreads();
  if (tid < 13){
    int sz = OFF[tid+1]-OFF[tid];
    double nr=0,ni=0;
    for(int i=0;i<sz;i++){ double r=sKr[OFF[tid]+i], im=sKi[OFF[tid]+i]; nr+=r*r; ni+=im*im; }
    int sel = (nr>=ni)? 0 : 1;
    sSel[tid]=sel;
    sScale[tid] = sqrt((double)(2*L3[tid]+1))/sqrt(sel? ni : nr);
  }
  __syncthreads();
  if (tid < 525){
    double v = sSel[combo]? sKi[tid] : sKr[tid];
    cg[tid] = (float)(v*sScale[combo]);
  }
}

// ============================================================================
// Weight prep: fp32 -> bf16 hi/lo planes. Linear weights transposed WT[o][k];
// TP weights [u][v].
// ============================================================================
__global__ void prep_kernel(const float* __restrict__ l2W0, const float* __restrict__ l2W1,
                            const float* __restrict__ l2W2, const float* __restrict__ LW0,
                            const float* __restrict__ LW1, const float* __restrict__ LW2,
                            const float* __restrict__ tpw, const float* __restrict__ tp4w,
                            unsigned short* __restrict__ wb){
  int i = blockIdx.x*256 + threadIdx.x;
  if (i >= W_TOT) return;
  float v;
  if (i < 8192){ int o=i>>7, k=i&127; v = l2W0[k*64+o]; }
  else if (i < 40960){ int j=i-8192; int o=j>>8, k=j&255; v = l2W1[k*128+o]; }
  else if (i < 49152){ int j=i-40960; int o=j>>7, k=j&127; v = l2W2[k*64+o]; }
  else if (i < 94208){ int j=i-49152; int li=j>>12, r=j&4095, o=r>>6, k=r&63; v = LW0[li*4096+k*64+o]; }
  else if (i < 274432){ int j=i-94208; int li=j>>14, r=j&16383, o=r>>7, k=r&127; v = LW1[li*16384+k*128+o]; }
  else if (i < 319488){ int j=i-274432; int li=j>>12, r=j&4095, o=r>>6, k=r&63; v = LW2[li*4096+k*64+o]; }
  else if (i < 491520){ v = tpw[i-319488]; }
  else { v = tp4w[i-491520]; }
  unsigned short h = f2b(v);
  wb[i] = h;
  wb[W_TOT + i] = f2b(v - b2f(h));
}

// ============================================================================
// lin1: x (fp32, 80) -> h1 (hi/lo bf16, stride 1536). One block per sample.
// ============================================================================
__global__ __launch_bounds__(256) void lin1_kernel(
    const float* __restrict__ x,
    const float* __restrict__ l1W0, const float* __restrict__ l1W1,
    const float* __restrict__ l1W2, const float* __restrict__ l1b0,
    unsigned short* __restrict__ h1h, unsigned short* __restrict__ h1l, int nb)
{
  const float rs8 = 0.3535533905932738f;
  int n = blockIdx.x;
  const float* xp = x + (size_t)(nb + n)*80;
  for (int c = threadIdx.x; c < 1536; c += 256){
    float acc = 0.f;
    if (c < 128){
      #pragma unroll
      for (int v=0;v<16;v++) acc += xp[v]*l1W0[v*128+c];
      acc = acc*0.25f + l1b0[c];
    } else if (c < 512){
      int i=(c-128)>>7, o=(c-128)&127;
      #pragma unroll
      for (int v=0;v<8;v++) acc += xp[16+v*3+i]*l1W1[v*256+o];
      acc *= rs8;
    } else if (c < 1152){
      int i=(c-512)>>7, o=(c-512)&127;
      #pragma unroll
      for (int v=0;v<8;v++) acc += xp[40+v*5+i]*l1W2[v*128+o];
      acc *= rs8;
    } else {
      int i=(c-1152)>>7, o=(c-1152)&127;
      #pragma unroll
      for (int v=0;v<8;v++) acc += xp[16+v*3+i]*l1W1[v*256+128+o];
      acc *= rs8;
    }
    store_hl(h1h, h1l, n*1536 + c, acc);
  }
}

// ============================================================================
// lin2: h1 (stride 1536) -> HID0 (stride 768). grid (CS/16, 4); job = y*4+wave.
// ============================================================================
__global__ __launch_bounds__(256) void lin2k_kernel(
    const unsigned short* __restrict__ wb, const float* __restrict__ b0,
    const unsigned short* __restrict__ sh, const unsigned short* __restrict__ sl,
    unsigned short* __restrict__ dh, unsigned short* __restrict__ dl)
{
  const float rs128 = 0.08838834764831845f;
  int lane = threadIdx.x & 63, wave = threadIdx.x >> 6;
  int job = blockIdx.y*4 + wave;
  int l16 = lane & 15, quad = lane >> 4;
  int nb16 = blockIdx.x*16;
  int arow = (nb16 + l16)*1536;
  if (job < 4){                 // l0: K=128, /sqrt(128) + bias
    int col = job*16 + l16;
    f32x4 a0 = {0,0,0,0}, a1 = {0,0,0,0};
    #pragma unroll
    for (int ks=0; ks<4; ks++){
      int so = arow + ks*32 + quad*8;
      bf16x8 xh = LDFRAG(sh+so), xl = LDFRAG(sl+so);
      int wo = OFF_L2W0 + col*128 + ks*32 + quad*8;
      bf16x8 wh = LDFRAG(wb+wo), wl = LDFRAG(wb+W_TOT+wo);
      a0 = mfma16(xh,wh,a0); a1 = mfma16(xh,wl,a1); a1 = mfma16(xl,wh,a1);
    }
    float bias = b0[col];
    #pragma unroll
    for (int r=0;r<4;r++)
      store_hl(dh,dl,(nb16+quad*4+r)*768 + col, (a0[r]+a1[r])*rs128 + bias);
  } else if (job < 12){         // l1: K=256 (l1|l1b), /16
    int col = (job-4)*16 + l16;
    #pragma unroll
    for (int i=0;i<3;i++){
      f32x4 a0 = {0,0,0,0}, a1 = {0,0,0,0};
      #pragma unroll
      for (int ks=0; ks<8; ks++){
        int ka = ks*32 + quad*8;
        int so = arow + ((ka < 128) ? (128 + i*128 + ka) : (1152 + i*128 + ka - 128));
        bf16x8 xh = LDFRAG(sh+so), xl = LDFRAG(sl+so);
        int wo = OFF_L2W1 + col*256 + ka;
        bf16x8 wh = LDFRAG(wb+wo), wl = LDFRAG(wb+W_TOT+wo);
        a0 = mfma16(xh,wh,a0); a1 = mfma16(xh,wl,a1); a1 = mfma16(xl,wh,a1);
      }
      int dof = (col < 64) ? (64 + i*64 + col) : (576 + i*64 + col - 64);
      #pragma unroll
      for (int r=0;r<4;r++)
        store_hl(dh,dl,(nb16+quad*4+r)*768 + dof, (a0[r]+a1[r])*0.0625f);
    }
  } else {                      // l2: K=128, /sqrt(128)
    int col = (job-12)*16 + l16;
    #pragma unroll
    for (int i=0;i<5;i++){
      f32x4 a0 = {0,0,0,0}, a1 = {0,0,0,0};
      #pragma unroll
      for (int ks=0; ks<4; ks++){
        int so = arow + 512 + i*128 + ks*32 + quad*8;
        bf16x8 xh = LDFRAG(sh+so), xl = LDFRAG(sl+so);
        int wo = OFF_L2W2 + col*128 + ks*32 + quad*8;
        bf16x8 wh = LDFRAG(wb+wo), wl = LDFRAG(wb+W_TOT+wo);
        a0 = mfma16(xh,wh,a0); a1 = mfma16(xh,wl,a1); a1 = mfma16(xl,wh,a1);
      }
      #pragma unroll
      for (int r=0;r<4;r++)
        store_hl(dh,dl,(nb16+quad*4+r)*768 + 256 + i*64 + col, (a0[r]+a1[r])*rs128);
    }
  }
}

// ============================================================================
// HID0 -> HID0 linear. grid (CS/16, 4); job = y*4+wave (0..15).
// ============================================================================
__global__ __launch_bounds__(256) void linh_kernel(
    const unsigned short* __restrict__ wb, int o0, int o1, int o2,
    const float* __restrict__ b0,
    const unsigned short* __restrict__ sh, const unsigned short* __restrict__ sl,
    unsigned short* __restrict__ dh, unsigned short* __restrict__ dl)
{
  const float rs128 = 0.08838834764831845f;
  int lane = threadIdx.x & 63, wave = threadIdx.x >> 6;
  int job = blockIdx.y*4 + wave;
  int l16 = lane & 15, quad = lane >> 4;
  int nb16 = blockIdx.x*16;
  int arow = (nb16 + l16)*768;
  if (job < 4){                 // l0: K=64, /8 + bias
    int col = job*16 + l16;
    f32x4 a0 = {0,0,0,0}, a1 = {0,0,0,0};
    #pragma unroll
    for (int ks=0; ks<2; ks++){
      int so = arow + ks*32 + quad*8;
      bf16x8 xh = LDFRAG(sh+so), xl = LDFRAG(sl+so);
      int wo = o0 + col*64 + ks*32 + quad*8;
      bf16x8 wh = LDFRAG(wb+wo), wl = LDFRAG(wb+W_TOT+wo);
      a0 = mfma16(xh,wh,a0); a1 = mfma16(xh,wl,a1); a1 = mfma16(xl,wh,a1);
    }
    float bias = b0[col];
    #pragma unroll
    for (int r=0;r<4;r++)
      store_hl(dh,dl,(nb16+quad*4+r)*768 + col, (a0[r]+a1[r])*0.125f + bias);
  } else if (job < 12){         // l1: K=128 (l1|l1b), /sqrt(128)
    int col = (job-4)*16 + l16;
    #pragma unroll
    for (int i=0;i<3;i++){
      f32x4 a0 = {0,0,0,0}, a1 = {0,0,0,0};
      #pragma unroll
      for (int ks=0; ks<4; ks++){
        int ka = ks*32 + quad*8;
        int so = arow + ((ka < 64) ? (64 + i*64 + ka) : (576 + i*64 + ka - 64));
        bf16x8 xh = LDFRAG(sh+so), xl = LDFRAG(sl+so);
        int wo = o1 + col*128 + ka;
        bf16x8 wh = LDFRAG(wb+wo), wl = LDFRAG(wb+W_TOT+wo);
        a0 = mfma16(xh,wh,a0); a1 = mfma16(xh,wl,a1); a1 = mfma16(xl,wh,a1);
      }
      int dof = (col < 64) ? (64 + i*64 + col) : (576 + i*64 + col - 64);
      #pragma unroll
      for (int r=0;r<4;r++)
        store_hl(dh,dl,(nb16+quad*4+r)*768 + dof, (a0[r]+a1[r])*rs128);
    }
  } else {                      // l2: K=64, /8
    int col = (job-12)*16 + l16;
    #pragma unroll
    for (int i=0;i<5;i++){
      f32x4 a0 = {0,0,0,0}, a1 = {0,0,0,0};
      #pragma unroll
      for (int ks=0; ks<2; ks++){
        int so = arow + 256 + i*64 + ks*32 + quad*8;
        bf16x8 xh = LDFRAG(sh+so), xl = LDFRAG(sl+so);
        int wo = o2 + col*64 + ks*32 + quad*8;
        bf16x8 wh = LDFRAG(wb+wo), wl = LDFRAG(wb+W_TOT+wo);
        a0 = mfma16(xh,wh,a0); a1 = mfma16(xh,wl,a1); a1 = mfma16(xl,wh,a1);
      }
      #pragma unroll
      for (int r=0;r<4;r++)
        store_hl(dh,dl,(nb16+quad*4+r)*768 + 256 + i*64 + col, (a0[r]+a1[r])*0.125f);
    }
  }
}

// ============================================================================
// TP path: wave mt does b = W(rows mt*16..+16) x x2 via hi/lo MFMA; the D
// fragment already sits at (u=mt*16+quad*4+r, n=l16) per lane, so the CG
// contraction consumes it directly from registers. tk layout: [r*D3+k].
// ============================================================================
template<int D1,int D2,int D3,int O1,int O2,int CGO>
__device__ __forceinline__ void tpg_path(
    const unsigned short* __restrict__ wb, int wo,
    const unsigned short* __restrict__ s1h, const unsigned short* __restrict__ s1l,
    const unsigned short* __restrict__ s2h, const unsigned short* __restrict__ s2l,
    const float* __restrict__ cgp, float* tk, int mt, int l16, int quad, int n)
{
  float x1v[4][D1];
  int ub = mt*16 + quad*4;
  #pragma unroll
  for (int i=0;i<D1;i++){
    int o = n*768 + O1 + i*64 + ub;
    u16x4 hs = *(const u16x4*)(s1h + o);
    u16x4 ls = *(const u16x4*)(s1l + o);
    #pragma unroll
    for (int r=0;r<4;r++) x1v[r][i] = b2f(hs[r]) + b2f(ls[r]);
  }
  #pragma unroll
  for (int j=0;j<D2;j++){
    f32x4 a0 = {0,0,0,0}, a1 = {0,0,0,0};
    #pragma unroll
    for (int ks=0;ks<2;ks++){
      int wofs = wo + (mt*16 + l16)*64 + ks*32 + quad*8;
      bf16x8 wh = LDFRAG(wb + wofs), wl = LDFRAG(wb + W_TOT + wofs);
      int sofs = n*768 + O2 + j*64 + ks*32 + quad*8;
      bf16x8 xh = LDFRAG(s2h + sofs), xl = LDFRAG(s2l + sofs);
      a0 = mfma16(wh,xh,a0); a1 = mfma16(wh,xl,a1); a1 = mfma16(wl,xh,a1);
    }
    #pragma unroll
    for (int r=0;r<4;r++){
      float bv = a0[r] + a1[r];
      #pragma unroll
      for (int i=0;i<D1;i++){
        float pr = x1v[r][i]*bv;
        #pragma unroll
        for (int k=0;k<D3;k++) tk[r*D3+k] += pr*cgp[CGO + (i*D2+j)*D3 + k];
      }
    }
  }
}

// uvu TP (one round). grid CS/16, block 256 (4 waves = 4 m-tiles). No barriers.
__global__ __launch_bounds__(256) void tpu_kernel(
    const unsigned short* __restrict__ wb, int two,
    const unsigned short* __restrict__ s1h, const unsigned short* __restrict__ s1l,
    const unsigned short* __restrict__ s2h, const unsigned short* __restrict__ s2l,
    unsigned short* __restrict__ dh, unsigned short* __restrict__ dl,
    const float* __restrict__ cgp)
{
  const float f192 = 0.07216878364870323f;  // 1/sqrt(192)
  const float f256 = 0.0625f;               // 1/sqrt(256)
  int lane = threadIdx.x & 63, mt = threadIdx.x >> 6;
  int l16 = lane & 15, quad = lane >> 4;
  int n = blockIdx.x*16 + l16;
  int ub = mt*16 + quad*4;
  { // out l0 @0 (fan 192): paths 0,5,10
    float tk[4]; for (int i=0;i<4;i++) tk[i]=0.f;
    tpg_path<1,1,1,  0,  0,  0>(wb,two+ 0*4096, s1h,s1l,s2h,s2l,cgp,tk,mt,l16,quad,n);
    tpg_path<3,3,1, 64, 64, 69>(wb,two+ 5*4096, s1h,s1l,s2h,s2l,cgp,tk,mt,l16,quad,n);
    tpg_path<5,5,1,256,256,300>(wb,two+10*4096, s1h,s1l,s2h,s2l,cgp,tk,mt,l16,quad,n);
    #pragma unroll
    for (int r=0;r<4;r++) store_hl(dh,dl, n*768 + ub + r, tk[r]*f192);
  }
  { // out l1 @64 (fan 256): paths 1,4,6,11
    float tk[12]; for (int i=0;i<12;i++) tk[i]=0.f;
    tpg_path<1,3,3,  0, 64,  1>(wb,two+ 1*4096, s1h,s1l,s2h,s2l,cgp,tk,mt,l16,quad,n);
    tpg_path<3,1,3, 64,  0, 10>(wb,two+ 4*4096, s1h,s1l,s2h,s2l,cgp,tk,mt,l16,quad,n);
    tpg_path<3,3,3, 64, 64, 78>(wb,two+ 6*4096, s1h,s1l,s2h,s2l,cgp,tk,mt,l16,quad,n);
    tpg_path<5,5,3,256,256,325>(wb,two+11*4096, s1h,s1l,s2h,s2l,cgp,tk,mt,l16,quad,n);
    #pragma unroll
    for (int r=0;r<4;r++)
      #pragma unroll
      for (int k=0;k<3;k++)
        store_hl(dh,dl, n*768 + 64 + k*64 + ub + r, tk[r*3+k]*f256);
  }
  { // out l2 @256 (fan 256): paths 2,8,9,13
    float tk[20]; for (int i=0;i<20;i++) tk[i]=0.f;
    tpg_path<1,5,5,  0,256, 19>(wb,two+ 2*4096, s1h,s1l,s2h,s2l,cgp,tk,mt,l16,quad,n);
    tpg_path<5,1,5,256,  0, 44>(wb,two+ 8*4096, s1h,s1l,s2h,s2l,cgp,tk,mt,l16,quad,n);
    tpg_path<5,3,5,256, 64,150>(wb,two+ 9*4096, s1h,s1l,s2h,s2l,cgp,tk,mt,l16,quad,n);
    tpg_path<5,3,5,256,576,150>(wb,two+13*4096, s1h,s1l,s2h,s2l,cgp,tk,mt,l16,quad,n);
    #pragma unroll
    for (int r=0;r<4;r++)
      #pragma unroll
      for (int k=0;k<5;k++)
        store_hl(dh,dl, n*768 + 256 + k*64 + ub + r, tk[r*5+k]*f256);
  }
  { // out l1b @576 (fan 192): paths 3,7,12
    float tk[12]; for (int i=0;i<12;i++) tk[i]=0.f;
    tpg_path<1,3,3,  0,576,  1>(wb,two+ 3*4096, s1h,s1l,s2h,s2l,cgp,tk,mt,l16,quad,n);
    tpg_path<3,3,3, 64, 64, 78>(wb,two+ 7*4096, s1h,s1l,s2h,s2l,cgp,tk,mt,l16,quad,n);
    tpg_path<5,5,3,256,256,325>(wb,two+12*4096, s1h,s1l,s2h,s2l,cgp,tk,mt,l16,quad,n);
    #pragma unroll
    for (int r=0;r<4;r++)
      #pragma unroll
      for (int k=0;k<3;k++)
        store_hl(dh,dl, n*768 + 576 + k*64 + ub + r, tk[r*3+k]*f192);
  }
}

// fully-connected TP -> out. grid CS/16, block 256. One LDS reduce + 1 barrier.
__global__ __launch_bounds__(256) void tpf_kernel(
    const unsigned short* __restrict__ wb,
    const unsigned short* __restrict__ s1h, const unsigned short* __restrict__ s1l,
    const unsigned short* __restrict__ s2h, const unsigned short* __restrict__ s2l,
    const float* __restrict__ cgp, float* __restrict__ out, int nb)
{
  __shared__ float red[4][16][6];
  int lane = threadIdx.x & 63, mt = threadIdx.x >> 6;
  int l16 = lane & 15, quad = lane >> 4;
  int n = blockIdx.x*16 + l16;
  { // out 0e (slot 0): fc paths 0..5
    float tk[4]; for (int i=0;i<4;i++) tk[i]=0.f;
    tpg_path<1,1,1,  0,  0,  0>(wb,OFF_TP4W+ 0*4096, s1h,s1l,s2h,s2l,cgp,tk,mt,l16,quad,n);
    tpg_path<3,3,1, 64, 64, 69>(wb,OFF_TP4W+ 1*4096, s1h,s1l,s2h,s2l,cgp,tk,mt,l16,quad,n);
    tpg_path<3,3,1, 64,576, 69>(wb,OFF_TP4W+ 2*4096, s1h,s1l,s2h,s2l,cgp,tk,mt,l16,quad,n);
    tpg_path<5,5,1,256,256,300>(wb,OFF_TP4W+ 3*4096, s1h,s1l,s2h,s2l,cgp,tk,mt,l16,quad,n);
    tpg_path<3,3,1,576, 64, 69>(wb,OFF_TP4W+ 4*4096, s1h,s1l,s2h,s2l,cgp,tk,mt,l16,quad,n);
    tpg_path<3,3,1,576,576, 69>(wb,OFF_TP4W+ 5*4096, s1h,s1l,s2h,s2l,cgp,tk,mt,l16,quad,n);
    float t = tk[0]+tk[1]+tk[2]+tk[3];
    t += __shfl_down(t, 32, 64);
    t += __shfl_down(t, 16, 64);
    if (lane < 16) red[mt][l16][0] = t;
  }
  { // out 2e (slots 1..5): fc paths 6..16
    float tk[20]; for (int i=0;i<20;i++) tk[i]=0.f;
    tpg_path<1,5,5,  0,256, 19>(wb,OFF_TP4W+ 6*4096, s1h,s1l,s2h,s2l,cgp,tk,mt,l16,quad,n);
    tpg_path<3,3,5, 64, 64,105>(wb,OFF_TP4W+ 7*4096, s1h,s1l,s2h,s2l,cgp,tk,mt,l16,quad,n);
    tpg_path<3,5,5, 64,256,225>(wb,OFF_TP4W+ 8*4096, s1h,s1l,s2h,s2l,cgp,tk,mt,l16,quad,n);
    tpg_path<3,3,5, 64,576,105>(wb,OFF_TP4W+ 9*4096, s1h,s1l,s2h,s2l,cgp,tk,mt,l16,quad,n);
    tpg_path<5,1,5,256,  0, 44>(wb,OFF_TP4W+10*4096, s1h,s1l,s2h,s2l,cgp,tk,mt,l16,quad,n);
    tpg_path<5,3,5,256, 64,150>(wb,OFF_TP4W+11*4096, s1h,s1l,s2h,s2l,cgp,tk,mt,l16,quad,n);
    tpg_path<5,5,5,256,256,400>(wb,OFF_TP4W+12*4096, s1h,s1l,s2h,s2l,cgp,tk,mt,l16,quad,n);
    tpg_path<5,3,5,256,576,150>(wb,OFF_TP4W+13*4096, s1h,s1l,s2h,s2l,cgp,tk,mt,l16,quad,n);
    tpg_path<3,3,5,576, 64,105>(wb,OFF_TP4W+14*4096, s1h,s1l,s2h,s2l,cgp,tk,mt,l16,quad,n);
    tpg_path<3,5,5,576,256,225>(wb,OFF_TP4W+15*4096, s1h,s1l,s2h,s2l,cgp,tk,mt,l16,quad,n);
    tpg_path<3,3,5,576,576,105>(wb,OFF_TP4W+16*4096, s1h,s1l,s2h,s2l,cgp,tk,mt,l16,quad,n);
    #pragma unroll
    for (int k=0;k<5;k++){
      float t = tk[k] + tk[5+k] + tk[10+k] + tk[15+k];
      t += __shfl_down(t, 32, 64);
      t += __shfl_down(t, 16, 64);
      if (lane < 16) red[mt][l16][1+k] = t;
    }
  }
  __syncthreads();
  if (threadIdx.x < 96){
    int n2 = threadIdx.x/6, k = threadIdx.x%6;
    float s = red[0][n2][k] + red[1][n2][k] + red[2][n2][k] + red[3][n2][k];
    float sc = (k==0)? (1.0f/sqrtf(24576.0f)) : (1.0f/sqrtf(45056.0f));
    out[(size_t)(nb + blockIdx.x*16 + n2)*6 + k] = s*sc;
  }
}

// ============================================================================
extern "C" void kernel_launch(void* const* d_in, const int* in_sizes, int n_in,
                              void* d_out, int out_size, void* d_ws, size_t ws_size,
                              hipStream_t stream)
{
  (void)n_in; (void)out_size;
  const float* x    = (const float*)d_in[0];
  const float* l1W0 = (const float*)d_in[1];
  const float* l1W1 = (const float*)d_in[2];
  const float* l1W2 = (const float*)d_in[3];
  const float* l1b0 = (const float*)d_in[4];
  const float* l2W0 = (const float*)d_in[5];
  const float* l2W1 = (const float*)d_in[6];
  const float* l2W2 = (const float*)d_in[7];
  const float* l2b0 = (const float*)d_in[8];
  const float* LW0  = (const float*)d_in[9];
  const float* LW1  = (const float*)d_in[10];
  const float* LW2  = (const float*)d_in[11];
  const float* Lb0  = (const float*)d_in[12];
  const float* tpw  = (const float*)d_in[13];
  const float* tp4w = (const float*)d_in[14];

  float* cg = (float*)d_ws;                                    // 525 f32 @ ws+0
  unsigned short* wbp = (unsigned short*)((char*)d_ws + 4096); // hi+lo weights
  size_t base = 4096 + (size_t)2*W_TOT*2;
  base = (base + 255) & ~(size_t)255;
  unsigned short* st = (unsigned short*)((char*)d_ws + base);
  size_t avail = (ws_size > base) ? (ws_size - base) : 0;

  const int total = in_sizes[0]/80;    // 16384
  int nch = 1, CS = total;
  // need 3 buffers x (hi+lo) x CS x 768 x 2B = 9216*CS bytes
  while (nch < 1024 && (size_t)CS * 9216 > avail){ nch <<= 1; CS = total / nch; }
  size_t P = (size_t)CS * 768;         // elements per plane

  cg_init_kernel<<<1, 576, 0, stream>>>(cg);
  prep_kernel<<<(W_TOT+255)/256, 256, 0, stream>>>(l2W0,l2W1,l2W2,LW0,LW1,LW2,tpw,tp4w,wbp);

  for (int c = 0; c < nch; c++){
    int nb = c*CS;
    unsigned short* h1h = st;          // spans buffer0 (hi+lo) regions: 2P
    unsigned short* h1l = st + 2*P;    // spans buffer1 regions: 2P
    #define BH(b) (st + (size_t)(2*(b))*P)
    #define BL(b) (st + (size_t)(2*(b)+1)*P)

    lin1_kernel<<<CS, 256, 0, stream>>>(x, l1W0,l1W1,l1W2,l1b0, h1h,h1l, nb);
    lin2k_kernel<<<dim3(CS/16,4), 256, 0, stream>>>(wbp, l2b0, h1h,h1l, BH(2),BL(2));

    int ih=2, i0=0, i1=1;
    for (int r=0;r<3;r++){
      linh_kernel<<<dim3(CS/16,4), 256, 0, stream>>>(wbp,
          OFF_LW0+(3*r  )*4096, OFF_LW1+(3*r  )*16384, OFF_LW2+(3*r  )*4096,
          Lb0+(3*r  )*64, BH(ih),BL(ih), BH(i0),BL(i0));
      linh_kernel<<<dim3(CS/16,4), 256, 0, stream>>>(wbp,
          OFF_LW0+(3*r+1)*4096, OFF_LW1+(3*r+1)*16384, OFF_LW2+(3*r+1)*4096,
          Lb0+(3*r+1)*64, BH(ih),BL(ih), BH(i1),BL(i1));
      tpu_kernel<<<CS/16, 256, 0, stream>>>(wbp, OFF_TPW + r*14*4096,
          BH(i0),BL(i0), BH(i1),BL(i1), BH(ih),BL(ih), cg);
      linh_kernel<<<dim3(CS/16,4), 256, 0, stream>>>(wbp,
          OFF_LW0+(3*r+2)*4096, OFF_LW1+(3*r+2)*16384, OFF_LW2+(3*r+2)*4096,
          Lb0+(3*r+2)*64, BH(ih),BL(ih), BH(i0),BL(i0));
      int nh=i0; i0=i1; i1=ih; ih=nh;
    }

    linh_kernel<<<dim3(CS/16,4), 256, 0, stream>>>(wbp,
        OFF_LW0+ 9*4096, OFF_LW1+ 9*16384, OFF_LW2+ 9*4096, Lb0+ 9*64,
        BH(ih),BL(ih), BH(i0),BL(i0));
    linh_kernel<<<dim3(CS/16,4), 256, 0, stream>>>(wbp,
        OFF_LW0+10*4096, OFF_LW1+10*16384, OFF_LW2+10*4096, Lb0+10*64,
        BH(ih),BL(ih), BH(i1),BL(i1));
    tpf_kernel<<<CS/16, 256, 0, stream>>>(wbp, BH(i0),BL(i0), BH(i1),BL(i1),
        cg, (float*)d_out, nb);
    #undef BH
    #undef BL
  }
}